// Round 7
// baseline (250.638 us; speedup 1.0000x reference)
//
#include <hip/hip_runtime.h>
#include <hip/hip_bf16.h>
#include <math.h>

// Problem constants
#define Bn  2
#define Tn  2048
#define Dn  1024
#define Hn  16
#define HDn 64
// M = B*T = 4096

typedef __attribute__((ext_vector_type(8))) short short8;
typedef __attribute__((ext_vector_type(8))) unsigned short u16x8;
typedef __attribute__((ext_vector_type(4))) unsigned short u16x4;
typedef __attribute__((ext_vector_type(4))) float f32x4;
typedef __attribute__((ext_vector_type(16))) float f32x16;
typedef unsigned short ushort_t;

#define MFMA16(a, b, c) __builtin_amdgcn_mfma_f32_16x16x32_bf16((a), (b), (c), 0, 0, 0)
#define MFMA32(a, b, c) __builtin_amdgcn_mfma_f32_32x32x16_bf16((a), (b), (c), 0, 0, 0)

__device__ __forceinline__ unsigned short f2b(float f) {
    union { float f; unsigned u; } v; v.f = f;
    unsigned r = (v.u + 0x7FFFu + ((v.u >> 16) & 1u)) >> 16;   // RNE
    return (unsigned short)r;
}
__device__ __forceinline__ float b2f(unsigned short h) {
    union { unsigned u; float f; } v; v.u = ((unsigned)h) << 16;
    return v.f;
}
__device__ __forceinline__ void gload_lds16(const void* g, void* l) {
    __builtin_amdgcn_global_load_lds(
        (const __attribute__((address_space(1))) void*)g,
        (__attribute__((address_space(3))) void*)l, 16, 0, 0);
}
__device__ __forceinline__ unsigned cvt_pk(float lo, float hi) {
    unsigned r;
    asm("v_cvt_pk_bf16_f32 %0, %1, %2" : "=v"(r) : "v"(lo), "v"(hi));
    return r;
}
// permlane32_swap with DISTINCT SSA values only (b==a would coalesce registers)
__device__ __forceinline__ void plswap(unsigned &a, unsigned &b) {
    asm volatile("v_permlane32_swap_b32 %0, %1" : "+v"(a), "+v"(b));
}
__device__ __forceinline__ float xhalf_max(float v) {
    return fmaxf(v, __shfl_xor(v, 32));
}
__device__ __forceinline__ float xhalf_add(float v) {
    return v + __shfl_xor(v, 32);
}

// ---------------------------------------------------------------------------
// x (f32) -> bf16, vectorized
// ---------------------------------------------------------------------------
__global__ __launch_bounds__(256) void cvt_bf16_kernel(
    const float* __restrict__ in, ushort_t* __restrict__ out)
{
    int i = blockIdx.x * 256 + threadIdx.x;
    const float4* p = (const float4*)in;
    float4 a = p[i * 2], b = p[i * 2 + 1];
    u16x8 o;
    o[0] = f2b(a.x); o[1] = f2b(a.y); o[2] = f2b(a.z); o[3] = f2b(a.w);
    o[4] = f2b(b.x); o[5] = f2b(b.y); o[6] = f2b(b.z); o[7] = f2b(b.w);
    *(u16x8*)&out[i * 8] = o;
}

// ---------------------------------------------------------------------------
// W (1024 x N, f32) -> Wt (N x 1024, bf16). 32x32 tiles, 256 threads.
// ---------------------------------------------------------------------------
__global__ __launch_bounds__(256) void transpose_kernel(
    const float* __restrict__ W, ushort_t* __restrict__ Wt, int N)
{
    __shared__ float tile[32][33];
    const int n0 = blockIdx.x * 32, k0 = blockIdx.y * 32;
    const int tx = threadIdx.x & 31, ty = threadIdx.x >> 5;
    #pragma unroll
    for (int i = 0; i < 4; ++i)
        tile[ty + i * 8][tx] = W[(size_t)(k0 + ty + i * 8) * N + n0 + tx];
    __syncthreads();
    #pragma unroll
    for (int i = 0; i < 4; ++i)
        Wt[(size_t)(n0 + ty + i * 8) * 1024 + k0 + tx] = f2b(tile[tx][ty + i * 8]);
}

// ---------------------------------------------------------------------------
// bf16 MFMA GEMM, m97 structure. EPI==0: QKV scatter with RoPE fused into
// the epilogue (pairs (hd, hd+32) live in acc[mi][nj] / acc[mi][nj+2]).
// ---------------------------------------------------------------------------
template <int EPI>   // 0 = QKV scatter (+RoPE on q,k), 1 = f32 C store
__global__ __launch_bounds__(256) void gemm_kernel(
    const ushort_t* __restrict__ A, const ushort_t* __restrict__ Bt,
    ushort_t* __restrict__ Qo, ushort_t* __restrict__ Ko, ushort_t* __restrict__ Vo,
    float* __restrict__ C, int Ncols)
{
    __shared__ __align__(16) ushort_t As[128 * 32];
    __shared__ __align__(16) ushort_t Bs[128 * 32];
    const int tid  = threadIdx.x;
    const int lane = tid & 63, wid = tid >> 6;
    const int l15 = lane & 15, lh = lane >> 4;
    const int wr = wid >> 1, wc = wid & 1;

    const int nbx = gridDim.x;
    const int nwg = nbx * gridDim.y;
    const int bid = blockIdx.y * nbx + blockIdx.x;
    const int cpx = nwg >> 3;
    const int swz = (bid & 7) * cpx + (bid >> 3);
    const int bm = (swz / nbx) * 128, bn = (swz % nbx) * 128;

    f32x4 acc[4][4];
    #pragma unroll
    for (int i = 0; i < 4; ++i)
        #pragma unroll
        for (int j = 0; j < 4; ++j) acc[i][j] = (f32x4){0.f, 0.f, 0.f, 0.f};

    const ushort_t* Ag = A  + (size_t)bm * 1024;
    const ushort_t* Bg = Bt + (size_t)bn * 1024;

    for (int k0 = 0; k0 < 1024; k0 += 32) {
        __syncthreads();
        #pragma unroll
        for (int i = 0; i < 2; ++i) {
            int idx = i * 256 + tid;
            int row = idx >> 2, kc = idx & 3;
            int src_k = k0 + ((kc ^ (row & 3)) * 8);
            gload_lds16(Ag + (size_t)row * 1024 + src_k, &As[idx * 8]);
            gload_lds16(Bg + (size_t)row * 1024 + src_k, &Bs[idx * 8]);
        }
        __syncthreads();

        short8 a[4], b[4];
        #pragma unroll
        for (int mi = 0; mi < 4; ++mi) {
            int ra = wr * 64 + mi * 16 + l15;
            a[mi] = *(const short8*)&As[ra * 32 + ((lh ^ (ra & 3)) * 8)];
        }
        #pragma unroll
        for (int nj = 0; nj < 4; ++nj) {
            int rb = wc * 64 + nj * 16 + l15;
            b[nj] = *(const short8*)&Bs[rb * 32 + ((lh ^ (rb & 3)) * 8)];
        }
        __builtin_amdgcn_s_setprio(1);
        #pragma unroll
        for (int mi = 0; mi < 4; ++mi)
            #pragma unroll
            for (int nj = 0; nj < 4; ++nj)
                acc[mi][nj] = MFMA16(a[mi], b[nj], acc[mi][nj]);
        __builtin_amdgcn_s_setprio(0);
    }

    if (EPI == 0) {
        const int n0 = bn + wc * 64;          // head-aligned 64-col block
        const int i3 = n0 >> 10;              // 0=q, 1=k, 2=v
        const int hh = (n0 >> 6) & 15;
        if (i3 == 2) {
            #pragma unroll
            for (int mi = 0; mi < 4; ++mi)
                #pragma unroll
                for (int r = 0; r < 4; ++r) {
                    int m = bm + wr * 64 + mi * 16 + lh * 4 + r;
                    int b_ = m >> 11, t = m & 2047;
                    size_t ob = ((size_t)((b_ * Hn + hh) * Tn) + t) * HDn;
                    #pragma unroll
                    for (int nj = 0; nj < 4; ++nj)
                        Vo[ob + nj * 16 + l15] = f2b(acc[mi][nj][r]);
                }
        } else {
            ushort_t* dst = i3 ? Ko : Qo;
            const float sc = i3 ? 1.0f : 0.125f;       // fold 1/sqrt(HD) into q
            const float inv0 = __powf(10000.0f, -(float)l15 * (1.0f / 32.0f));
            const float inv1 = __powf(10000.0f, -(float)(16 + l15) * (1.0f / 32.0f));
            #pragma unroll
            for (int mi = 0; mi < 4; ++mi)
                #pragma unroll
                for (int r = 0; r < 4; ++r) {
                    int m = bm + wr * 64 + mi * 16 + lh * 4 + r;
                    int b_ = m >> 11, t = m & 2047;
                    size_t ob = ((size_t)((b_ * Hn + hh) * Tn) + t) * HDn;
                    float tf = (float)t;
                    #pragma unroll
                    for (int nj = 0; nj < 2; ++nj) {
                        float fr = tf * (nj ? inv1 : inv0);
                        float cc, ss;
                        __sincosf(fr, &ss, &cc);
                        float v0 = acc[mi][nj][r], v1 = acc[mi][nj + 2][r];
                        int j = nj * 16 + l15;
                        dst[ob + j]      = f2b((v0 * cc - v1 * ss) * sc);
                        dst[ob + j + 32] = f2b((v1 * cc + v0 * ss) * sc);
                    }
                }
        }
    } else {
        #pragma unroll
        for (int mi = 0; mi < 4; ++mi)
            #pragma unroll
            for (int nj = 0; nj < 4; ++nj)
                #pragma unroll
                for (int r = 0; r < 4; ++r) {
                    int m = bm + wr * 64 + mi * 16 + lh * 4 + r;
                    int n = bn + wc * 64 + nj * 16 + l15;
                    C[(size_t)m * 1024 + n] = acc[mi][nj][r];
                }
    }
}

// ---------------------------------------------------------------------------
// Flash attention v4: balanced dual-state groups.
// Grid (32 bh fast, 16 x). 512 threads = 8 waves: wave = (par=wid>>2,
// h2=(wid>>1)&1, sub=wid&1). Wave processes the concatenated tile list
// [qtA tiles kt%2==par, then qtB tiles kt%2==par], keys [h2*32, h2*32+32),
// q rows (state q-tile)*64 + sub*32 + l31. Every wave: 16/17 tiles -> no
// idling; every block: exactly 17 iterations. Two accumulator states
// (poA/poB); Q-frags reloaded at the uniform A->B switch. 4-way merge
// (par x h2) per state through LDS carve, 2 rounds.
// ---------------------------------------------------------------------------
#define ATTN_STEP(PO, MM, LL)                                                   \
  do {                                                                          \
    f32x16 st;                                                                  \
    _Pragma("unroll") for (int k = 0; k < 16; ++k) st[k] = 0.f;                 \
    __builtin_amdgcn_s_setprio(1);                                              \
    {                                                                           \
      const int keyr = h2 * 32 + l31;                                          \
      const ushort_t* kbase = &Ks_c[cur * 4096 + keyr * 64];                    \
      _Pragma("unroll") for (int dk = 0; dk < 4; ++dk) {                        \
        short8 kf = *(const short8*)(kbase + (((dk * 2 + h) ^ (l31 & 7)) * 8)); \
        st = MFMA32(kf, qf[dk], st);                                            \
      }                                                                         \
    }                                                                           \
    __builtin_amdgcn_s_setprio(0);                                              \
    if (kt == qt_cur) {                                                         \
      const int qloc = sub * 32 + l31;                                          \
      _Pragma("unroll") for (int r = 0; r < 16; ++r) {                          \
        int keyloc = h2 * 32 + (r & 3) + 8 * (r >> 2) + 4 * h;                  \
        if (keyloc > qloc) st[r] = -1e30f;                                      \
      }                                                                         \
    }                                                                           \
    float t8[8];                                                                \
    _Pragma("unroll") for (int k = 0; k < 8; ++k) t8[k] = fmaxf(st[k], st[k + 8]); \
    _Pragma("unroll") for (int stp = 4; stp >= 1; stp >>= 1)                    \
      _Pragma("unroll") for (int k = 0; k < stp; ++k) t8[k] = fmaxf(t8[k], t8[k + stp]); \
    float mt = xhalf_max(t8[0]);                                                \
    float mnew = fmaxf(MM, mt);                                                 \
    float cr = __expf(MM - mnew);                                               \
    MM = mnew;                                                                  \
    _Pragma("unroll") for (int k = 0; k < 16; ++k) st[k] = __expf(st[k] - mnew); \
    _Pragma("unroll") for (int k = 0; k < 8; ++k) t8[k] = st[k] + st[k + 8];    \
    _Pragma("unroll") for (int stp = 4; stp >= 1; stp >>= 1)                    \
      _Pragma("unroll") for (int k = 0; k < stp; ++k) t8[k] += t8[k + stp];     \
    float ls = xhalf_add(t8[0]);                                                \
    LL = LL * cr + ls;                                                          \
    _Pragma("unroll") for (int db = 0; db < 2; ++db)                            \
      _Pragma("unroll") for (int k = 0; k < 16; ++k) PO[db][k] *= cr;           \
    {                                                                           \
      unsigned w0 = cvt_pk(st[0], st[1]);   unsigned w1 = cvt_pk(st[2], st[3]); \
      unsigned w2 = cvt_pk(st[4], st[5]);   unsigned w3 = cvt_pk(st[6], st[7]); \
      unsigned w4 = cvt_pk(st[8], st[9]);   unsigned w5 = cvt_pk(st[10], st[11]); \
      unsigned w6 = cvt_pk(st[12], st[13]); unsigned w7 = cvt_pk(st[14], st[15]); \
      plswap(w0, w2); plswap(w1, w3); plswap(w4, w6); plswap(w5, w7);           \
      union { unsigned u[4]; short8 s8; } f0, f1;                               \
      f0.u[0] = w0; f0.u[1] = w1; f0.u[2] = w2; f0.u[3] = w3;                   \
      f1.u[0] = w4; f1.u[1] = w5; f1.u[2] = w6; f1.u[3] = w7;                   \
      __builtin_amdgcn_s_setprio(1);                                            \
      _Pragma("unroll") for (int db = 0; db < 2; ++db) {                        \
        const int d = db * 32 + l31;                                            \
        const int ck0 = 4 * h2 + h;                                             \
        short8 vf0 = *(const short8*)&Vt_c[cur * 64 + d][((ck0 + (d >> 3)) & 7) * 8]; \
        PO[db] = MFMA32(vf0, f0.s8, PO[db]);                                    \
        const int ck1 = 4 * h2 + 2 + h;                                         \
        short8 vf1 = *(const short8*)&Vt_c[cur * 64 + d][((ck1 + (d >> 3)) & 7) * 8]; \
        PO[db] = MFMA32(vf1, f1.s8, PO[db]);                                    \
      }                                                                         \
      __builtin_amdgcn_s_setprio(0);                                            \
    }                                                                           \
  } while (0)

#define DUMP_STATE(PO, MM, LL)                                                  \
  do {                                                                          \
    float* dstp = carve + (size_t)(wid - 2) * 2176 + lane * 34;                 \
    dstp[0] = MM; dstp[1] = LL;                                                 \
    _Pragma("unroll") for (int db = 0; db < 2; ++db)                            \
      _Pragma("unroll") for (int k = 0; k < 16; ++k)                            \
        dstp[2 + db * 16 + k] = PO[db][k];                                      \
  } while (0)

#define MERGE_STORE(PO, MM, LL, QT)                                            \
  do {                                                                          \
    const float* p0 = carve + (size_t)(wid + 0) * 2176 + lane * 34;             \
    const float* p1 = carve + (size_t)(wid + 2) * 2176 + lane * 34;             \
    const float* p2 = carve + (size_t)(wid + 4) * 2176 + lane * 34;             \
    float m0 = p0[0], l0 = p0[1], m1 = p1[0], l1 = p1[1], m2 = p2[0], l2 = p2[1]; \
    float mf = fmaxf(fmaxf(MM, m0), fmaxf(m1, m2));                             \
    float c  = __expf(MM - mf), c0 = __expf(m0 - mf);                           \
    float c1 = __expf(m1 - mf), c2 = __expf(m2 - mf);                           \
    float lf = LL * c + l0 * c0 + l1 * c1 + l2 * c2;                            \
    float inv = 1.0f / lf;                                                      \
    const int qg2 = (QT) * 64 + wid * 32 + l31;                                 \
    ushort_t* orow = AO + ((size_t)(b_ * Tn + qg2)) * Dn + head * HDn;          \
    _Pragma("unroll") for (int db = 0; db < 2; ++db) {                          \
      _Pragma("unroll") for (int rq = 0; rq < 4; ++rq) {                        \
        u16x4 o4;                                                               \
        _Pragma("unroll") for (int rr = 0; rr < 4; ++rr) {                      \
          int k = rq * 4 + rr;                                                  \
          float v = (PO[db][k] * c + p0[2 + db * 16 + k] * c0 +                 \
                     p1[2 + db * 16 + k] * c1 + p2[2 + db * 16 + k] * c2) * inv; \
          o4[rr] = f2b(v);                                                      \
        }                                                                       \
        *(u16x4*)&orow[db * 32 + 8 * rq + 4 * h] = o4;                          \
      }                                                                         \
    }                                                                           \
  } while (0)

__global__ __launch_bounds__(512, 4) void attn_kernel(
    const ushort_t* __restrict__ Q, const ushort_t* __restrict__ K,
    const ushort_t* __restrict__ V, ushort_t* __restrict__ AO)
{
    __shared__ __align__(16) char smem[69632];
    ushort_t* KsE = (ushort_t*)smem;                          // [2][4096]
    ushort_t (*VtE)[72] = (ushort_t(*)[72])(smem + 16384);    // [2][64][72]
    ushort_t* KsO = (ushort_t*)(smem + 34816);
    ushort_t (*VtO)[72] = (ushort_t(*)[72])(smem + 51200);
    float* carve = (float*)smem;                              // merge reuse

    const int tid = threadIdx.x;
    const int lane = tid & 63, wid = tid >> 6;
    const int l31 = lane & 31, h = lane >> 5;
    const int bh = blockIdx.x;                // XCD = bh%8 (bh fast)
    const int x = blockIdx.y;                 // 0..15
    const int qtA = x, qtB = 31 - x;
    const int sub = wid & 1, h2 = (wid >> 1) & 1, par = wid >> 2;
    const size_t base = (size_t)bh * (Tn * HDn);

    // per-parity tile lists: [qtA kt%2==par] ++ [qtB kt%2==par]
    const int a_par = (qtA >= par) ? ((qtA - par) >> 1) + 1 : 0;
    const int len_par = a_par + ((qtB - par) >> 1) + 1;

    // staging stream of this thread (E: tid<256, O: tid>=256)
    const int s = tid >> 8;
    const int ltid = tid & 255;
    const int a_s = (qtA >= s) ? ((qtA - s) >> 1) + 1 : 0;
    const int len_s = a_s + ((qtB - s) >> 1) + 1;
    ushort_t* Ks_s = s ? KsO : KsE;
    ushort_t (*Vt_s)[72] = s ? VtO : VtE;
    ushort_t* Ks_c = par ? KsO : KsE;
    ushort_t (*Vt_c)[72] = par ? VtO : VtE;
    const int vkp = (ltid >> 3) * 2, vc = ltid & 7;

    // initial Q fragments (state A if it has tiles, else straight to B)
    short8 qf[4];
    {
        const int qt0 = (a_par > 0) ? qtA : qtB;
        const ushort_t* qp = Q + base + (size_t)(qt0 * 64 + sub * 32 + l31) * 64 + h * 8;
        #pragma unroll
        for (int dk = 0; dk < 4; ++dk) qf[dk] = *(const short8*)(qp + dk * 16);
    }

    f32x16 poA[2], poB[2];
    #pragma unroll
    for (int db = 0; db < 2; ++db)
        #pragma unroll
        for (int k = 0; k < 16; ++k) { poA[db][k] = 0.f; poB[db][k] = 0.f; }
    float mA = -INFINITY, lA = 0.f, mB = -INFINITY, lB = 0.f;

    u16x8 va, vb;
    // ---- prologue: stage tile kt = s into buffer 0 ----
    {
        const ushort_t* ks = K + base + (size_t)s * 4096;
        #pragma unroll
        for (int i = 0; i < 2; ++i) {
            int idx = i * 256 + ltid, key = idx >> 3, c = idx & 7;
            gload_lds16(ks + key * 64 + ((c ^ (key & 7)) * 8), &Ks_s[idx * 8]);
        }
        const ushort_t* v0 = V + base + (size_t)s * 4096 + (size_t)vkp * 64 + vc * 8;
        va = *(const u16x8*)v0;
        vb = *(const u16x8*)(v0 + 64);
        #pragma unroll
        for (int j = 0; j < 8; ++j) {
            int d = vc * 8 + j;
            unsigned w = (unsigned)va[j] | ((unsigned)vb[j] << 16);
            int blk = ((vkp >> 3) + (d >> 3)) & 7;
            *(unsigned*)&Vt_s[d][blk * 8 + (vkp & 7)] = w;
        }
    }
    __syncthreads();

    for (int i = 0; i < 17; ++i) {
        const int cur = i & 1;
        const bool doPf = (i + 1 < len_s);
        if (doPf) {
            const int in = i + 1;
            const int ktn = (in < a_s) ? (2 * in + s) : (2 * (in - a_s) + s);
            const ushort_t* ks = K + base + (size_t)ktn * 4096;
            #pragma unroll
            for (int ii = 0; ii < 2; ++ii) {
                int idx = ii * 256 + ltid, key = idx >> 3, c = idx & 7;
                gload_lds16(ks + key * 64 + ((c ^ (key & 7)) * 8),
                            &Ks_s[(cur ^ 1) * 4096 + idx * 8]);
            }
            const ushort_t* v0 = V + base + (size_t)ktn * 4096 + (size_t)vkp * 64 + vc * 8;
            va = *(const u16x8*)v0;
            vb = *(const u16x8*)(v0 + 64);
        }

        if (i < len_par) {
            const bool inA = (i < a_par);
            if (a_par > 0 && i == a_par) {     // uniform A->B switch: reload Q
                const ushort_t* qp = Q + base +
                    (size_t)(qtB * 64 + sub * 32 + l31) * 64 + h * 8;
                #pragma unroll
                for (int dk = 0; dk < 4; ++dk) qf[dk] = *(const short8*)(qp + dk * 16);
            }
            const int qt_cur = inA ? qtA : qtB;
            const int kt = inA ? (2 * i + par) : (2 * (i - a_par) + par);
            const bool live = !(kt == qt_cur && h2 > sub);   // fully-masked half
            if (live) {
                if (inA) { ATTN_STEP(poA, mA, lA); }
                else     { ATTN_STEP(poB, mB, lB); }
            }
        }

        if (doPf) {
            #pragma unroll
            for (int j = 0; j < 8; ++j) {
                int d = vc * 8 + j;
                unsigned w = (unsigned)va[j] | ((unsigned)vb[j] << 16);
                int blk = ((vkp >> 3) + (d >> 3)) & 7;
                *(unsigned*)&Vt_s[(cur ^ 1) * 64 + d][blk * 8 + (vkp & 7)] = w;
            }
        }
        __syncthreads();
    }

    // ---- 4-way merge (par x h2) per state, 2 rounds ----
    const int b_ = bh >> 4, head = bh & 15;
    if (wid >= 2) { DUMP_STATE(poA, mA, lA); }
    __syncthreads();
    if (wid < 2)  { MERGE_STORE(poA, mA, lA, qtA); }
    __syncthreads();
    if (wid >= 2) { DUMP_STATE(poB, mB, lB); }
    __syncthreads();
    if (wid < 2)  { MERGE_STORE(poB, mB, lB, qtB); }
}

// ---------------------------------------------------------------------------
extern "C" void kernel_launch(void* const* d_in, const int* in_sizes, int n_in,
                              void* d_out, int out_size, void* d_ws, size_t ws_size,
                              hipStream_t stream)
{
    const float* x     = (const float*)d_in[0];
    const float* Wqkv  = (const float*)d_in[1];
    const float* Wproj = (const float*)d_in[2];
    float* out = (float*)d_out;

    ushort_t* ws = (ushort_t*)d_ws;
    ushort_t* xb     = ws;
    ushort_t* Wqkvt  = xb     + 4194304;
    ushort_t* Wprojt = Wqkvt  + 3145728;
    ushort_t* Qb     = Wprojt + 1048576;
    ushort_t* Kb     = Qb     + 4194304;
    ushort_t* Vb     = Kb     + 4194304;
    ushort_t* AOb    = Vb     + 4194304;

    cvt_bf16_kernel<<<524288 / 256, 256, 0, stream>>>(x, xb);
    transpose_kernel<<<dim3(3072 / 32, 32), 256, 0, stream>>>(Wqkv, Wqkvt, 3072);
    transpose_kernel<<<dim3(1024 / 32, 32), 256, 0, stream>>>(Wproj, Wprojt, 1024);

    // QKV projection with fused RoPE (rope_kernel eliminated)
    gemm_kernel<0><<<dim3(3072 / 128, 4096 / 128), 256, 0, stream>>>(
        xb, Wqkvt, Qb, Kb, Vb, nullptr, 3072);

    // flash attention (balanced dual-state groups), bh-major grid
    attn_kernel<<<dim3(Bn * Hn, 16), 512, 0, stream>>>(Qb, Kb, Vb, AOb);

    gemm_kernel<1><<<dim3(1024 / 128, 4096 / 128), 256, 0, stream>>>(
        AOb, Wprojt, nullptr, nullptr, nullptr, out, 1024);
}

// Round 8
// 131.347 us; speedup vs baseline: 1.9082x; 1.9082x over previous
//
#include <hip/hip_runtime.h>
#include <hip/hip_bf16.h>
#include <math.h>

// Problem constants
#define Bn  2
#define Tn  2048
#define Dn  1024
#define Hn  16
#define HDn 64
// M = B*T = 4096

typedef __attribute__((ext_vector_type(8))) short short8;
typedef __attribute__((ext_vector_type(8))) unsigned short u16x8;
typedef __attribute__((ext_vector_type(4))) unsigned short u16x4;
typedef __attribute__((ext_vector_type(4))) float f32x4;
typedef __attribute__((ext_vector_type(16))) float f32x16;
typedef unsigned short ushort_t;

#define MFMA16(a, b, c) __builtin_amdgcn_mfma_f32_16x16x32_bf16((a), (b), (c), 0, 0, 0)
#define MFMA32(a, b, c) __builtin_amdgcn_mfma_f32_32x32x16_bf16((a), (b), (c), 0, 0, 0)

__device__ __forceinline__ unsigned short f2b(float f) {
    union { float f; unsigned u; } v; v.f = f;
    unsigned r = (v.u + 0x7FFFu + ((v.u >> 16) & 1u)) >> 16;   // RNE
    return (unsigned short)r;
}
__device__ __forceinline__ float b2f(unsigned short h) {
    union { unsigned u; float f; } v; v.u = ((unsigned)h) << 16;
    return v.f;
}
__device__ __forceinline__ void gload_lds16(const void* g, void* l) {
    __builtin_amdgcn_global_load_lds(
        (const __attribute__((address_space(1))) void*)g,
        (__attribute__((address_space(3))) void*)l, 16, 0, 0);
}
__device__ __forceinline__ unsigned cvt_pk(float lo, float hi) {
    unsigned r;
    asm("v_cvt_pk_bf16_f32 %0, %1, %2" : "=v"(r) : "v"(lo), "v"(hi));
    return r;
}
// permlane32_swap with DISTINCT SSA values only (b==a would coalesce registers)
__device__ __forceinline__ void plswap(unsigned &a, unsigned &b) {
    asm volatile("v_permlane32_swap_b32 %0, %1" : "+v"(a), "+v"(b));
}
__device__ __forceinline__ float xhalf_max(float v) {
    return fmaxf(v, __shfl_xor(v, 32));
}
__device__ __forceinline__ float xhalf_add(float v) {
    return v + __shfl_xor(v, 32);
}

// ---------------------------------------------------------------------------
// x (f32) -> bf16, vectorized
// ---------------------------------------------------------------------------
__global__ __launch_bounds__(256) void cvt_bf16_kernel(
    const float* __restrict__ in, ushort_t* __restrict__ out)
{
    int i = blockIdx.x * 256 + threadIdx.x;
    const float4* p = (const float4*)in;
    float4 a = p[i * 2], b = p[i * 2 + 1];
    u16x8 o;
    o[0] = f2b(a.x); o[1] = f2b(a.y); o[2] = f2b(a.z); o[3] = f2b(a.w);
    o[4] = f2b(b.x); o[5] = f2b(b.y); o[6] = f2b(b.z); o[7] = f2b(b.w);
    *(u16x8*)&out[i * 8] = o;
}

// ---------------------------------------------------------------------------
// W (1024 x N, f32) -> Wt (N x 1024, bf16). 32x32 tiles, 256 threads.
// ---------------------------------------------------------------------------
__global__ __launch_bounds__(256) void transpose_kernel(
    const float* __restrict__ W, ushort_t* __restrict__ Wt, int N)
{
    __shared__ float tile[32][33];
    const int n0 = blockIdx.x * 32, k0 = blockIdx.y * 32;
    const int tx = threadIdx.x & 31, ty = threadIdx.x >> 5;
    #pragma unroll
    for (int i = 0; i < 4; ++i)
        tile[ty + i * 8][tx] = W[(size_t)(k0 + ty + i * 8) * N + n0 + tx];
    __syncthreads();
    #pragma unroll
    for (int i = 0; i < 4; ++i)
        Wt[(size_t)(n0 + ty + i * 8) * 1024 + k0 + tx] = f2b(tile[tx][ty + i * 8]);
}

// ---------------------------------------------------------------------------
// bf16 MFMA GEMM, m97 structure. EPI==0: QKV scatter with RoPE fused into
// the epilogue (pairs (hd, hd+32) live in acc[mi][nj] / acc[mi][nj+2]).
// ---------------------------------------------------------------------------
template <int EPI>   // 0 = QKV scatter (+RoPE on q,k), 1 = f32 C store
__global__ __launch_bounds__(256) void gemm_kernel(
    const ushort_t* __restrict__ A, const ushort_t* __restrict__ Bt,
    ushort_t* __restrict__ Qo, ushort_t* __restrict__ Ko, ushort_t* __restrict__ Vo,
    float* __restrict__ C, int Ncols)
{
    __shared__ __align__(16) ushort_t As[128 * 32];
    __shared__ __align__(16) ushort_t Bs[128 * 32];
    const int tid  = threadIdx.x;
    const int lane = tid & 63, wid = tid >> 6;
    const int l15 = lane & 15, lh = lane >> 4;
    const int wr = wid >> 1, wc = wid & 1;

    const int nbx = gridDim.x;
    const int nwg = nbx * gridDim.y;
    const int bid = blockIdx.y * nbx + blockIdx.x;
    const int cpx = nwg >> 3;
    const int swz = (bid & 7) * cpx + (bid >> 3);
    const int bm = (swz / nbx) * 128, bn = (swz % nbx) * 128;

    f32x4 acc[4][4];
    #pragma unroll
    for (int i = 0; i < 4; ++i)
        #pragma unroll
        for (int j = 0; j < 4; ++j) acc[i][j] = (f32x4){0.f, 0.f, 0.f, 0.f};

    const ushort_t* Ag = A  + (size_t)bm * 1024;
    const ushort_t* Bg = Bt + (size_t)bn * 1024;

    for (int k0 = 0; k0 < 1024; k0 += 32) {
        __syncthreads();
        #pragma unroll
        for (int i = 0; i < 2; ++i) {
            int idx = i * 256 + tid;
            int row = idx >> 2, kc = idx & 3;
            int src_k = k0 + ((kc ^ (row & 3)) * 8);
            gload_lds16(Ag + (size_t)row * 1024 + src_k, &As[idx * 8]);
            gload_lds16(Bg + (size_t)row * 1024 + src_k, &Bs[idx * 8]);
        }
        __syncthreads();

        short8 a[4], b[4];
        #pragma unroll
        for (int mi = 0; mi < 4; ++mi) {
            int ra = wr * 64 + mi * 16 + l15;
            a[mi] = *(const short8*)&As[ra * 32 + ((lh ^ (ra & 3)) * 8)];
        }
        #pragma unroll
        for (int nj = 0; nj < 4; ++nj) {
            int rb = wc * 64 + nj * 16 + l15;
            b[nj] = *(const short8*)&Bs[rb * 32 + ((lh ^ (rb & 3)) * 8)];
        }
        __builtin_amdgcn_s_setprio(1);
        #pragma unroll
        for (int mi = 0; mi < 4; ++mi)
            #pragma unroll
            for (int nj = 0; nj < 4; ++nj)
                acc[mi][nj] = MFMA16(a[mi], b[nj], acc[mi][nj]);
        __builtin_amdgcn_s_setprio(0);
    }

    if (EPI == 0) {
        const int n0 = bn + wc * 64;          // head-aligned 64-col block
        const int i3 = n0 >> 10;              // 0=q, 1=k, 2=v
        const int hh = (n0 >> 6) & 15;
        if (i3 == 2) {
            #pragma unroll
            for (int mi = 0; mi < 4; ++mi)
                #pragma unroll
                for (int r = 0; r < 4; ++r) {
                    int m = bm + wr * 64 + mi * 16 + lh * 4 + r;
                    int b_ = m >> 11, t = m & 2047;
                    size_t ob = ((size_t)((b_ * Hn + hh) * Tn) + t) * HDn;
                    #pragma unroll
                    for (int nj = 0; nj < 4; ++nj)
                        Vo[ob + nj * 16 + l15] = f2b(acc[mi][nj][r]);
                }
        } else {
            ushort_t* dst = i3 ? Ko : Qo;
            const float sc = i3 ? 1.0f : 0.125f;       // fold 1/sqrt(HD) into q
            const float inv0 = __powf(10000.0f, -(float)l15 * (1.0f / 32.0f));
            const float inv1 = __powf(10000.0f, -(float)(16 + l15) * (1.0f / 32.0f));
            #pragma unroll
            for (int mi = 0; mi < 4; ++mi)
                #pragma unroll
                for (int r = 0; r < 4; ++r) {
                    int m = bm + wr * 64 + mi * 16 + lh * 4 + r;
                    int b_ = m >> 11, t = m & 2047;
                    size_t ob = ((size_t)((b_ * Hn + hh) * Tn) + t) * HDn;
                    float tf = (float)t;
                    #pragma unroll
                    for (int nj = 0; nj < 2; ++nj) {
                        float fr = tf * (nj ? inv1 : inv0);
                        float cc, ss;
                        __sincosf(fr, &ss, &cc);
                        float v0 = acc[mi][nj][r], v1 = acc[mi][nj + 2][r];
                        int j = nj * 16 + l15;
                        dst[ob + j]      = f2b((v0 * cc - v1 * ss) * sc);
                        dst[ob + j + 32] = f2b((v1 * cc + v0 * ss) * sc);
                    }
                }
        }
    } else {
        #pragma unroll
        for (int mi = 0; mi < 4; ++mi)
            #pragma unroll
            for (int nj = 0; nj < 4; ++nj)
                #pragma unroll
                for (int r = 0; r < 4; ++r) {
                    int m = bm + wr * 64 + mi * 16 + lh * 4 + r;
                    int n = bn + wc * 64 + nj * 16 + l15;
                    C[(size_t)m * 1024 + n] = acc[mi][nj][r];
                }
    }
}

// ---------------------------------------------------------------------------
// Flash attention v5: one q-tile per block, parity-split KV, single state.
// Grid (32 bh fast, 32 slot), qt = 31 - slot (big blocks dispatch first ->
// LPT backfill absorbs the 1..16-iteration imbalance; 1024 blocks, 2/CU).
// 512 threads = 8 waves: wave = (par=wid>>2, h2=(wid>>1)&1, sub=wid&1):
// keys [h2*32, +32) of tiles kt%2==par, q rows qt*64 + sub*32 + l31.
// nIter = qt/2+1; all waves busy every iteration (minus odd-parity tail and
// fully-masked diagonal halves). Staging: stream E (tid<256) stages even
// tiles, O stages odd. 4-way merge (par x h2) per sub via LDS, one round.
// ---------------------------------------------------------------------------
#define ATTN_STEP(PO, MM, LL)                                                   \
  do {                                                                          \
    f32x16 st;                                                                  \
    _Pragma("unroll") for (int k = 0; k < 16; ++k) st[k] = 0.f;                 \
    __builtin_amdgcn_s_setprio(1);                                              \
    {                                                                           \
      const int keyr = h2 * 32 + l31;                                          \
      const ushort_t* kbase = &Ks_c[cur * 4096 + keyr * 64];                    \
      _Pragma("unroll") for (int dk = 0; dk < 4; ++dk) {                        \
        short8 kf = *(const short8*)(kbase + (((dk * 2 + h) ^ (l31 & 7)) * 8)); \
        st = MFMA32(kf, qf[dk], st);                                            \
      }                                                                         \
    }                                                                           \
    __builtin_amdgcn_s_setprio(0);                                              \
    if (kt == qt) {                                                             \
      const int qloc = sub * 32 + l31;                                          \
      _Pragma("unroll") for (int r = 0; r < 16; ++r) {                          \
        int keyloc = h2 * 32 + (r & 3) + 8 * (r >> 2) + 4 * h;                  \
        if (keyloc > qloc) st[r] = -1e30f;                                      \
      }                                                                         \
    }                                                                           \
    float t8[8];                                                                \
    _Pragma("unroll") for (int k = 0; k < 8; ++k) t8[k] = fmaxf(st[k], st[k + 8]); \
    _Pragma("unroll") for (int stp = 4; stp >= 1; stp >>= 1)                    \
      _Pragma("unroll") for (int k = 0; k < stp; ++k) t8[k] = fmaxf(t8[k], t8[k + stp]); \
    float mt = xhalf_max(t8[0]);                                                \
    float mnew = fmaxf(MM, mt);                                                 \
    float cr = __expf(MM - mnew);                                               \
    MM = mnew;                                                                  \
    _Pragma("unroll") for (int k = 0; k < 16; ++k) st[k] = __expf(st[k] - mnew); \
    _Pragma("unroll") for (int k = 0; k < 8; ++k) t8[k] = st[k] + st[k + 8];    \
    _Pragma("unroll") for (int stp = 4; stp >= 1; stp >>= 1)                    \
      _Pragma("unroll") for (int k = 0; k < stp; ++k) t8[k] += t8[k + stp];     \
    float ls = xhalf_add(t8[0]);                                                \
    LL = LL * cr + ls;                                                          \
    _Pragma("unroll") for (int db = 0; db < 2; ++db)                            \
      _Pragma("unroll") for (int k = 0; k < 16; ++k) PO[db][k] *= cr;           \
    {                                                                           \
      unsigned w0 = cvt_pk(st[0], st[1]);   unsigned w1 = cvt_pk(st[2], st[3]); \
      unsigned w2 = cvt_pk(st[4], st[5]);   unsigned w3 = cvt_pk(st[6], st[7]); \
      unsigned w4 = cvt_pk(st[8], st[9]);   unsigned w5 = cvt_pk(st[10], st[11]); \
      unsigned w6 = cvt_pk(st[12], st[13]); unsigned w7 = cvt_pk(st[14], st[15]); \
      plswap(w0, w2); plswap(w1, w3); plswap(w4, w6); plswap(w5, w7);           \
      union { unsigned u[4]; short8 s8; } f0, f1;                               \
      f0.u[0] = w0; f0.u[1] = w1; f0.u[2] = w2; f0.u[3] = w3;                   \
      f1.u[0] = w4; f1.u[1] = w5; f1.u[2] = w6; f1.u[3] = w7;                   \
      __builtin_amdgcn_s_setprio(1);                                            \
      _Pragma("unroll") for (int db = 0; db < 2; ++db) {                        \
        const int d = db * 32 + l31;                                            \
        const int ck0 = 4 * h2 + h;                                             \
        short8 vf0 = *(const short8*)&Vt_c[cur * 64 + d][((ck0 + (d >> 3)) & 7) * 8]; \
        PO[db] = MFMA32(vf0, f0.s8, PO[db]);                                    \
        const int ck1 = 4 * h2 + 2 + h;                                         \
        short8 vf1 = *(const short8*)&Vt_c[cur * 64 + d][((ck1 + (d >> 3)) & 7) * 8]; \
        PO[db] = MFMA32(vf1, f1.s8, PO[db]);                                    \
      }                                                                         \
      __builtin_amdgcn_s_setprio(0);                                            \
    }                                                                           \
  } while (0)

__global__ __launch_bounds__(512, 4) void attn_kernel(
    const ushort_t* __restrict__ Q, const ushort_t* __restrict__ K,
    const ushort_t* __restrict__ V, ushort_t* __restrict__ AO)
{
    __shared__ __align__(16) char smem[69632];
    ushort_t* KsE = (ushort_t*)smem;                          // [2][4096]
    ushort_t (*VtE)[72] = (ushort_t(*)[72])(smem + 16384);    // [2][64][72]
    ushort_t* KsO = (ushort_t*)(smem + 34816);
    ushort_t (*VtO)[72] = (ushort_t(*)[72])(smem + 51200);
    float* carve = (float*)smem;                              // merge reuse

    const int tid = threadIdx.x;
    const int lane = tid & 63, wid = tid >> 6;
    const int l31 = lane & 31, h = lane >> 5;
    const int bh = blockIdx.x;                // XCD = bh%8 (bh fast)
    const int qt = 31 - blockIdx.y;           // big blocks first (LPT backfill)
    const int sub = wid & 1, h2 = (wid >> 1) & 1, par = wid >> 2;
    const size_t base = (size_t)bh * (Tn * HDn);
    const int nIter = (qt >> 1) + 1;

    // staging stream of this thread (E: tid<256 stages even kt, O: odd kt)
    const int s = tid >> 8;
    const int ltid = tid & 255;
    ushort_t* Ks_s = s ? KsO : KsE;
    ushort_t (*Vt_s)[72] = s ? VtO : VtE;
    ushort_t* Ks_c = par ? KsO : KsE;
    ushort_t (*Vt_c)[72] = par ? VtO : VtE;
    const int vkp = (ltid >> 3) * 2, vc = ltid & 7;

    // Q fragments (q-tile fixed for whole block)
    short8 qf[4];
    {
        const ushort_t* qp = Q + base + (size_t)(qt * 64 + sub * 32 + l31) * 64 + h * 8;
        #pragma unroll
        for (int dk = 0; dk < 4; ++dk) qf[dk] = *(const short8*)(qp + dk * 16);
    }

    f32x16 po[2];
    #pragma unroll
    for (int db = 0; db < 2; ++db)
        #pragma unroll
        for (int k = 0; k < 16; ++k) po[db][k] = 0.f;
    float m = -INFINITY, l = 0.f;

    u16x8 va, vb;
    // ---- prologue: stream s stages tile kt = s into buffer 0 ----
    {
        const ushort_t* ks = K + base + (size_t)s * 4096;
        #pragma unroll
        for (int i = 0; i < 2; ++i) {
            int idx = i * 256 + ltid, key = idx >> 3, c = idx & 7;
            gload_lds16(ks + key * 64 + ((c ^ (key & 7)) * 8), &Ks_s[idx * 8]);
        }
        const ushort_t* v0 = V + base + (size_t)s * 4096 + (size_t)vkp * 64 + vc * 8;
        va = *(const u16x8*)v0;
        vb = *(const u16x8*)(v0 + 64);
        #pragma unroll
        for (int j = 0; j < 8; ++j) {
            int d = vc * 8 + j;
            unsigned w = (unsigned)va[j] | ((unsigned)vb[j] << 16);
            int blk = ((vkp >> 3) + (d >> 3)) & 7;
            *(unsigned*)&Vt_s[d][blk * 8 + (vkp & 7)] = w;
        }
    }
    __syncthreads();

    for (int i = 0; i < nIter; ++i) {
        const int cur = i & 1;
        const int ktn = 2 * (i + 1) + s;          // this stream's next tile
        const bool doPf = (ktn <= qt);
        if (doPf) {
            const ushort_t* ks = K + base + (size_t)ktn * 4096;
            #pragma unroll
            for (int ii = 0; ii < 2; ++ii) {
                int idx = ii * 256 + ltid, key = idx >> 3, c = idx & 7;
                gload_lds16(ks + key * 64 + ((c ^ (key & 7)) * 8),
                            &Ks_s[(cur ^ 1) * 4096 + idx * 8]);
            }
            const ushort_t* v0 = V + base + (size_t)ktn * 4096 + (size_t)vkp * 64 + vc * 8;
            va = *(const u16x8*)v0;
            vb = *(const u16x8*)(v0 + 64);
        }

        const int kt = 2 * i + par;
        if (kt <= qt && !(kt == qt && h2 > sub)) {
            ATTN_STEP(po, m, l);
        }

        if (doPf) {
            #pragma unroll
            for (int j = 0; j < 8; ++j) {
                int d = vc * 8 + j;
                unsigned w = (unsigned)va[j] | ((unsigned)vb[j] << 16);
                int blk = ((vkp >> 3) + (d >> 3)) & 7;
                *(unsigned*)&Vt_s[(cur ^ 1) * 64 + d][blk * 8 + (vkp & 7)] = w;
            }
        }
        __syncthreads();
    }

    // ---- 4-way merge (par x h2) per sub, one round ----
    const int b_ = bh >> 4, head = bh & 15;
    if (wid >= 2) {
        float* dstp = carve + (size_t)(wid - 2) * 2176 + lane * 34;
        dstp[0] = m; dstp[1] = l;
        #pragma unroll
        for (int db = 0; db < 2; ++db)
            #pragma unroll
            for (int k = 0; k < 16; ++k) dstp[2 + db * 16 + k] = po[db][k];
    }
    __syncthreads();
    if (wid < 2) {
        const float* p0 = carve + (size_t)(wid + 0) * 2176 + lane * 34;
        const float* p1 = carve + (size_t)(wid + 2) * 2176 + lane * 34;
        const float* p2 = carve + (size_t)(wid + 4) * 2176 + lane * 34;
        float m0 = p0[0], l0 = p0[1], m1 = p1[0], l1 = p1[1], m2 = p2[0], l2 = p2[1];
        float mf = fmaxf(fmaxf(m, m0), fmaxf(m1, m2));
        float c  = __expf(m - mf), c0 = __expf(m0 - mf);
        float c1 = __expf(m1 - mf), c2 = __expf(m2 - mf);
        float lf = l * c + l0 * c0 + l1 * c1 + l2 * c2;
        float inv = 1.0f / lf;
        const int qg2 = qt * 64 + wid * 32 + l31;
        ushort_t* orow = AO + ((size_t)(b_ * Tn + qg2)) * Dn + head * HDn;
        #pragma unroll
        for (int db = 0; db < 2; ++db) {
            #pragma unroll
            for (int rq = 0; rq < 4; ++rq) {
                u16x4 o4;
                #pragma unroll
                for (int rr = 0; rr < 4; ++rr) {
                    int k = rq * 4 + rr;
                    float v = (po[db][k] * c + p0[2 + db * 16 + k] * c0 +
                               p1[2 + db * 16 + k] * c1 + p2[2 + db * 16 + k] * c2) * inv;
                    o4[rr] = f2b(v);
                }
                *(u16x4*)&orow[db * 32 + 8 * rq + 4 * h] = o4;
            }
        }
    }
}

// ---------------------------------------------------------------------------
extern "C" void kernel_launch(void* const* d_in, const int* in_sizes, int n_in,
                              void* d_out, int out_size, void* d_ws, size_t ws_size,
                              hipStream_t stream)
{
    const float* x     = (const float*)d_in[0];
    const float* Wqkv  = (const float*)d_in[1];
    const float* Wproj = (const float*)d_in[2];
    float* out = (float*)d_out;

    ushort_t* ws = (ushort_t*)d_ws;
    ushort_t* xb     = ws;
    ushort_t* Wqkvt  = xb     + 4194304;
    ushort_t* Wprojt = Wqkvt  + 3145728;
    ushort_t* Qb     = Wprojt + 1048576;
    ushort_t* Kb     = Qb     + 4194304;
    ushort_t* Vb     = Kb     + 4194304;
    ushort_t* AOb    = Vb     + 4194304;

    cvt_bf16_kernel<<<524288 / 256, 256, 0, stream>>>(x, xb);
    transpose_kernel<<<dim3(3072 / 32, 32), 256, 0, stream>>>(Wqkv, Wqkvt, 3072);
    transpose_kernel<<<dim3(1024 / 32, 32), 256, 0, stream>>>(Wproj, Wprojt, 1024);

    // QKV projection with fused RoPE
    gemm_kernel<0><<<dim3(3072 / 128, 4096 / 128), 256, 0, stream>>>(
        xb, Wqkvt, Qb, Kb, Vb, nullptr, 3072);

    // flash attention: one q-tile per block, big-first dispatch, bh-major
    attn_kernel<<<dim3(Bn * Hn, 32), 512, 0, stream>>>(Qb, Kb, Vb, AOb);

    gemm_kernel<1><<<dim3(1024 / 128, 4096 / 128), 256, 0, stream>>>(
        AOb, Wprojt, nullptr, nullptr, nullptr, out, 1024);
}

// Round 9
// 128.950 us; speedup vs baseline: 1.9437x; 1.0186x over previous
//
#include <hip/hip_runtime.h>
#include <hip/hip_bf16.h>
#include <math.h>

// Problem constants
#define Bn  2
#define Tn  2048
#define Dn  1024
#define Hn  16
#define HDn 64
// M = B*T = 4096

typedef __attribute__((ext_vector_type(8))) short short8;
typedef __attribute__((ext_vector_type(8))) unsigned short u16x8;
typedef __attribute__((ext_vector_type(4))) unsigned short u16x4;
typedef __attribute__((ext_vector_type(4))) float f32x4;
typedef __attribute__((ext_vector_type(16))) float f32x16;
typedef unsigned short ushort_t;

#define MFMA16(a, b, c) __builtin_amdgcn_mfma_f32_16x16x32_bf16((a), (b), (c), 0, 0, 0)
#define MFMA32(a, b, c) __builtin_amdgcn_mfma_f32_32x32x16_bf16((a), (b), (c), 0, 0, 0)

__device__ __forceinline__ unsigned short f2b(float f) {
    union { float f; unsigned u; } v; v.f = f;
    unsigned r = (v.u + 0x7FFFu + ((v.u >> 16) & 1u)) >> 16;   // RNE
    return (unsigned short)r;
}
__device__ __forceinline__ float b2f(unsigned short h) {
    union { unsigned u; float f; } v; v.u = ((unsigned)h) << 16;
    return v.f;
}
__device__ __forceinline__ void gload_lds16(const void* g, void* l) {
    __builtin_amdgcn_global_load_lds(
        (const __attribute__((address_space(1))) void*)g,
        (__attribute__((address_space(3))) void*)l, 16, 0, 0);
}
__device__ __forceinline__ unsigned cvt_pk(float lo, float hi) {
    unsigned r;
    asm("v_cvt_pk_bf16_f32 %0, %1, %2" : "=v"(r) : "v"(lo), "v"(hi));
    return r;
}
// permlane32_swap with DISTINCT SSA values only (b==a would coalesce registers)
__device__ __forceinline__ void plswap(unsigned &a, unsigned &b) {
    asm volatile("v_permlane32_swap_b32 %0, %1" : "+v"(a), "+v"(b));
}
__device__ __forceinline__ float xhalf_max(float v) {
    return fmaxf(v, __shfl_xor(v, 32));
}
__device__ __forceinline__ float xhalf_add(float v) {
    return v + __shfl_xor(v, 32);
}

// ---------------------------------------------------------------------------
// x (f32) -> bf16, vectorized
// ---------------------------------------------------------------------------
__global__ __launch_bounds__(256) void cvt_bf16_kernel(
    const float* __restrict__ in, ushort_t* __restrict__ out)
{
    int i = blockIdx.x * 256 + threadIdx.x;
    const float4* p = (const float4*)in;
    float4 a = p[i * 2], b = p[i * 2 + 1];
    u16x8 o;
    o[0] = f2b(a.x); o[1] = f2b(a.y); o[2] = f2b(a.z); o[3] = f2b(a.w);
    o[4] = f2b(b.x); o[5] = f2b(b.y); o[6] = f2b(b.z); o[7] = f2b(b.w);
    *(u16x8*)&out[i * 8] = o;
}

// ---------------------------------------------------------------------------
// W (1024 x N, f32) -> Wt (N x 1024, bf16). 32x32 tiles, 256 threads.
// ---------------------------------------------------------------------------
__global__ __launch_bounds__(256) void transpose_kernel(
    const float* __restrict__ W, ushort_t* __restrict__ Wt, int N)
{
    __shared__ float tile[32][33];
    const int n0 = blockIdx.x * 32, k0 = blockIdx.y * 32;
    const int tx = threadIdx.x & 31, ty = threadIdx.x >> 5;
    #pragma unroll
    for (int i = 0; i < 4; ++i)
        tile[ty + i * 8][tx] = W[(size_t)(k0 + ty + i * 8) * N + n0 + tx];
    __syncthreads();
    #pragma unroll
    for (int i = 0; i < 4; ++i)
        Wt[(size_t)(n0 + ty + i * 8) * 1024 + k0 + tx] = f2b(tile[tx][ty + i * 8]);
}

// ---------------------------------------------------------------------------
// bf16 MFMA GEMM, m97 structure. EPI==0: QKV scatter with RoPE fused.
// 2-D XCD chunking: each XCD owns an (gridDim.y/4) x (nbx/2) block region ->
// per-XCD working set ~5MB (A-chunk stays L2-resident across the bn sweep).
// Requires gridDim.y % 4 == 0 and nbx % 2 == 0 (both grids satisfy).
// ---------------------------------------------------------------------------
template <int EPI>   // 0 = QKV scatter (+RoPE on q,k), 1 = f32 C store
__global__ __launch_bounds__(256) void gemm_kernel(
    const ushort_t* __restrict__ A, const ushort_t* __restrict__ Bt,
    ushort_t* __restrict__ Qo, ushort_t* __restrict__ Ko, ushort_t* __restrict__ Vo,
    float* __restrict__ C, int Ncols)
{
    __shared__ __align__(16) ushort_t As[128 * 32];
    __shared__ __align__(16) ushort_t Bs[128 * 32];
    const int tid  = threadIdx.x;
    const int lane = tid & 63, wid = tid >> 6;
    const int l15 = lane & 15, lh = lane >> 4;
    const int wr = wid >> 1, wc = wid & 1;

    // 2-D XCD chunk mapping (XCD = linear block id % 8)
    const int nbx = gridDim.x;
    const int bid = blockIdx.y * nbx + blockIdx.x;
    const int xcd = bid & 7, r = bid >> 3;
    const int xm = xcd >> 1, xn = xcd & 1;       // 4 x 2 XCD regions
    const int bmc = gridDim.y >> 2;              // bm rows per region
    const int bnc = nbx >> 1;                    // bn cols per region
    const int rm = r % bmc, rn = r / bmc;        // bm fast -> B panel reused
    const int bm = (xm * bmc + rm) * 128;
    const int bn = (xn * bnc + rn) * 128;

    f32x4 acc[4][4];
    #pragma unroll
    for (int i = 0; i < 4; ++i)
        #pragma unroll
        for (int j = 0; j < 4; ++j) acc[i][j] = (f32x4){0.f, 0.f, 0.f, 0.f};

    const ushort_t* Ag = A  + (size_t)bm * 1024;
    const ushort_t* Bg = Bt + (size_t)bn * 1024;

    for (int k0 = 0; k0 < 1024; k0 += 32) {
        __syncthreads();
        #pragma unroll
        for (int i = 0; i < 2; ++i) {
            int idx = i * 256 + tid;
            int row = idx >> 2, kc = idx & 3;
            int src_k = k0 + ((kc ^ (row & 3)) * 8);
            gload_lds16(Ag + (size_t)row * 1024 + src_k, &As[idx * 8]);
            gload_lds16(Bg + (size_t)row * 1024 + src_k, &Bs[idx * 8]);
        }
        __syncthreads();

        short8 a[4], b[4];
        #pragma unroll
        for (int mi = 0; mi < 4; ++mi) {
            int ra = wr * 64 + mi * 16 + l15;
            a[mi] = *(const short8*)&As[ra * 32 + ((lh ^ (ra & 3)) * 8)];
        }
        #pragma unroll
        for (int nj = 0; nj < 4; ++nj) {
            int rb = wc * 64 + nj * 16 + l15;
            b[nj] = *(const short8*)&Bs[rb * 32 + ((lh ^ (rb & 3)) * 8)];
        }
        __builtin_amdgcn_s_setprio(1);
        #pragma unroll
        for (int mi = 0; mi < 4; ++mi)
            #pragma unroll
            for (int nj = 0; nj < 4; ++nj)
                acc[mi][nj] = MFMA16(a[mi], b[nj], acc[mi][nj]);
        __builtin_amdgcn_s_setprio(0);
    }

    if (EPI == 0) {
        const int n0 = bn + wc * 64;          // head-aligned 64-col block
        const int i3 = n0 >> 10;              // 0=q, 1=k, 2=v
        const int hh = (n0 >> 6) & 15;
        if (i3 == 2) {
            #pragma unroll
            for (int mi = 0; mi < 4; ++mi)
                #pragma unroll
                for (int r2 = 0; r2 < 4; ++r2) {
                    int m = bm + wr * 64 + mi * 16 + lh * 4 + r2;
                    int b_ = m >> 11, t = m & 2047;
                    size_t ob = ((size_t)((b_ * Hn + hh) * Tn) + t) * HDn;
                    #pragma unroll
                    for (int nj = 0; nj < 4; ++nj)
                        Vo[ob + nj * 16 + l15] = f2b(acc[mi][nj][r2]);
                }
        } else {
            ushort_t* dst = i3 ? Ko : Qo;
            const float sc = i3 ? 1.0f : 0.125f;       // fold 1/sqrt(HD) into q
            const float inv0 = __powf(10000.0f, -(float)l15 * (1.0f / 32.0f));
            const float inv1 = __powf(10000.0f, -(float)(16 + l15) * (1.0f / 32.0f));
            #pragma unroll
            for (int mi = 0; mi < 4; ++mi)
                #pragma unroll
                for (int r2 = 0; r2 < 4; ++r2) {
                    int m = bm + wr * 64 + mi * 16 + lh * 4 + r2;
                    int b_ = m >> 11, t = m & 2047;
                    size_t ob = ((size_t)((b_ * Hn + hh) * Tn) + t) * HDn;
                    float tf = (float)t;
                    #pragma unroll
                    for (int nj = 0; nj < 2; ++nj) {
                        float fr = tf * (nj ? inv1 : inv0);
                        float cc, ss;
                        __sincosf(fr, &ss, &cc);
                        float v0 = acc[mi][nj][r2], v1 = acc[mi][nj + 2][r2];
                        int j = nj * 16 + l15;
                        dst[ob + j]      = f2b((v0 * cc - v1 * ss) * sc);
                        dst[ob + j + 32] = f2b((v1 * cc + v0 * ss) * sc);
                    }
                }
        }
    } else {
        #pragma unroll
        for (int mi = 0; mi < 4; ++mi)
            #pragma unroll
            for (int nj = 0; nj < 4; ++nj)
                #pragma unroll
                for (int r2 = 0; r2 < 4; ++r2) {
                    int m = bm + wr * 64 + mi * 16 + lh * 4 + r2;
                    int n = bn + wc * 64 + nj * 16 + l15;
                    C[(size_t)m * 1024 + n] = acc[mi][nj][r2];
                }
    }
}

// ---------------------------------------------------------------------------
// Flash attention v5.1: one q-tile per block, parity-split KV, single state,
// SINGLE-buffered Vt (K stays double-buffered) -> LDS 52KB -> 3 blocks/CU.
// Loop: {issue K(i+1) gload_lds -> Ks[cur^1]; load V(i+1) -> regs;
//        compute on Ks[cur], Vt; barrier; write Vt <- V(i+1); barrier}.
// Grid (32 bh fast, 32 slot), qt = 31 - slot (LPT backfill), XCD = bh%8.
// 512 threads = 8 waves (par, h2, sub). 4-way merge via LDS carve.
// ---------------------------------------------------------------------------
#define ATTN_STEP(PO, MM, LL)                                                   \
  do {                                                                          \
    f32x16 st;                                                                  \
    _Pragma("unroll") for (int k = 0; k < 16; ++k) st[k] = 0.f;                 \
    __builtin_amdgcn_s_setprio(1);                                              \
    {                                                                           \
      const int keyr = h2 * 32 + l31;                                          \
      const ushort_t* kbase = &Ks_c[cur * 4096 + keyr * 64];                    \
      _Pragma("unroll") for (int dk = 0; dk < 4; ++dk) {                        \
        short8 kf = *(const short8*)(kbase + (((dk * 2 + h) ^ (l31 & 7)) * 8)); \
        st = MFMA32(kf, qf[dk], st);                                            \
      }                                                                         \
    }                                                                           \
    __builtin_amdgcn_s_setprio(0);                                              \
    if (kt == qt) {                                                             \
      const int qloc = sub * 32 + l31;                                          \
      _Pragma("unroll") for (int r = 0; r < 16; ++r) {                          \
        int keyloc = h2 * 32 + (r & 3) + 8 * (r >> 2) + 4 * h;                  \
        if (keyloc > qloc) st[r] = -1e30f;                                      \
      }                                                                         \
    }                                                                           \
    float t8[8];                                                                \
    _Pragma("unroll") for (int k = 0; k < 8; ++k) t8[k] = fmaxf(st[k], st[k + 8]); \
    _Pragma("unroll") for (int stp = 4; stp >= 1; stp >>= 1)                    \
      _Pragma("unroll") for (int k = 0; k < stp; ++k) t8[k] = fmaxf(t8[k], t8[k + stp]); \
    float mt = xhalf_max(t8[0]);                                                \
    float mnew = fmaxf(MM, mt);                                                 \
    float cr = __expf(MM - mnew);                                               \
    MM = mnew;                                                                  \
    _Pragma("unroll") for (int k = 0; k < 16; ++k) st[k] = __expf(st[k] - mnew); \
    _Pragma("unroll") for (int k = 0; k < 8; ++k) t8[k] = st[k] + st[k + 8];    \
    _Pragma("unroll") for (int stp = 4; stp >= 1; stp >>= 1)                    \
      _Pragma("unroll") for (int k = 0; k < stp; ++k) t8[k] += t8[k + stp];     \
    float ls = xhalf_add(t8[0]);                                                \
    LL = LL * cr + ls;                                                          \
    _Pragma("unroll") for (int db = 0; db < 2; ++db)                            \
      _Pragma("unroll") for (int k = 0; k < 16; ++k) PO[db][k] *= cr;           \
    {                                                                           \
      unsigned w0 = cvt_pk(st[0], st[1]);   unsigned w1 = cvt_pk(st[2], st[3]); \
      unsigned w2 = cvt_pk(st[4], st[5]);   unsigned w3 = cvt_pk(st[6], st[7]); \
      unsigned w4 = cvt_pk(st[8], st[9]);   unsigned w5 = cvt_pk(st[10], st[11]); \
      unsigned w6 = cvt_pk(st[12], st[13]); unsigned w7 = cvt_pk(st[14], st[15]); \
      plswap(w0, w2); plswap(w1, w3); plswap(w4, w6); plswap(w5, w7);           \
      union { unsigned u[4]; short8 s8; } f0, f1;                               \
      f0.u[0] = w0; f0.u[1] = w1; f0.u[2] = w2; f0.u[3] = w3;                   \
      f1.u[0] = w4; f1.u[1] = w5; f1.u[2] = w6; f1.u[3] = w7;                   \
      __builtin_amdgcn_s_setprio(1);                                            \
      _Pragma("unroll") for (int db = 0; db < 2; ++db) {                        \
        const int d = db * 32 + l31;                                            \
        const int ck0 = 4 * h2 + h;                                             \
        short8 vf0 = *(const short8*)&Vt_c[d][((ck0 + (d >> 3)) & 7) * 8];      \
        PO[db] = MFMA32(vf0, f0.s8, PO[db]);                                    \
        const int ck1 = 4 * h2 + 2 + h;                                         \
        short8 vf1 = *(const short8*)&Vt_c[d][((ck1 + (d >> 3)) & 7) * 8];      \
        PO[db] = MFMA32(vf1, f1.s8, PO[db]);                                    \
      }                                                                         \
      __builtin_amdgcn_s_setprio(0);                                            \
    }                                                                           \
  } while (0)

__global__ __launch_bounds__(512, 4) void attn_kernel(
    const ushort_t* __restrict__ Q, const ushort_t* __restrict__ K,
    const ushort_t* __restrict__ V, ushort_t* __restrict__ AO)
{
    __shared__ __align__(16) char smem[52224];
    ushort_t* KsE = (ushort_t*)smem;                          // [2][4096] = 16384 B
    ushort_t (*VtE)[72] = (ushort_t(*)[72])(smem + 16384);    // [64][72]  =  9216 B
    ushort_t* KsO = (ushort_t*)(smem + 25600);                // 16384 B
    ushort_t (*VtO)[72] = (ushort_t(*)[72])(smem + 41984);    //  9216 B (end 51200)
    float* carve = (float*)smem;                              // merge: 52224 B

    const int tid = threadIdx.x;
    const int lane = tid & 63, wid = tid >> 6;
    const int l31 = lane & 31, h = lane >> 5;
    const int bh = blockIdx.x;                // XCD = bh%8 (bh fast)
    const int qt = 31 - blockIdx.y;           // big blocks first (LPT backfill)
    const int sub = wid & 1, h2 = (wid >> 1) & 1, par = wid >> 2;
    const size_t base = (size_t)bh * (Tn * HDn);
    const int nIter = (qt >> 1) + 1;

    // staging stream of this thread (E: tid<256 stages even kt, O: odd kt)
    const int s = tid >> 8;
    const int ltid = tid & 255;
    ushort_t* Ks_s = s ? KsO : KsE;
    ushort_t (*Vt_s)[72] = s ? VtO : VtE;
    ushort_t* Ks_c = par ? KsO : KsE;
    ushort_t (*Vt_c)[72] = par ? VtO : VtE;
    const int vkp = (ltid >> 3) * 2, vc = ltid & 7;

    // Q fragments (q-tile fixed for whole block)
    short8 qf[4];
    {
        const ushort_t* qp = Q + base + (size_t)(qt * 64 + sub * 32 + l31) * 64 + h * 8;
        #pragma unroll
        for (int dk = 0; dk < 4; ++dk) qf[dk] = *(const short8*)(qp + dk * 16);
    }

    f32x16 po[2];
    #pragma unroll
    for (int db = 0; db < 2; ++db)
        #pragma unroll
        for (int k = 0; k < 16; ++k) po[db][k] = 0.f;
    float m = -INFINITY, l = 0.f;

    u16x8 va, vb;
    // ---- prologue: stream s stages tile kt = s ----
    {
        const ushort_t* ks = K + base + (size_t)s * 4096;
        #pragma unroll
        for (int i = 0; i < 2; ++i) {
            int idx = i * 256 + ltid, key = idx >> 3, c = idx & 7;
            gload_lds16(ks + key * 64 + ((c ^ (key & 7)) * 8), &Ks_s[idx * 8]);
        }
        const ushort_t* v0 = V + base + (size_t)s * 4096 + (size_t)vkp * 64 + vc * 8;
        va = *(const u16x8*)v0;
        vb = *(const u16x8*)(v0 + 64);
        #pragma unroll
        for (int j = 0; j < 8; ++j) {
            int d = vc * 8 + j;
            unsigned w = (unsigned)va[j] | ((unsigned)vb[j] << 16);
            int blk = ((vkp >> 3) + (d >> 3)) & 7;
            *(unsigned*)&Vt_s[d][blk * 8 + (vkp & 7)] = w;
        }
    }
    __syncthreads();

    for (int i = 0; i < nIter; ++i) {
        const int cur = i & 1;
        const int ktn = 2 * (i + 1) + s;          // this stream's next tile
        const bool doPf = (ktn <= qt);
        if (doPf) {
            // K prefetch into the other K buffer (safe: last read at iter i-1)
            const ushort_t* ks = K + base + (size_t)ktn * 4096;
            #pragma unroll
            for (int ii = 0; ii < 2; ++ii) {
                int idx = ii * 256 + ltid, key = idx >> 3, c = idx & 7;
                gload_lds16(ks + key * 64 + ((c ^ (key & 7)) * 8),
                            &Ks_s[(cur ^ 1) * 4096 + idx * 8]);
            }
            // V prefetch into registers (no LDS race)
            const ushort_t* v0 = V + base + (size_t)ktn * 4096 + (size_t)vkp * 64 + vc * 8;
            va = *(const u16x8*)v0;
            vb = *(const u16x8*)(v0 + 64);
        }

        const int kt = 2 * i + par;
        if (kt <= qt && !(kt == qt && h2 > sub)) {
            ATTN_STEP(po, m, l);
        }

        __syncthreads();                          // all waves done reading Vt
        if (doPf) {
            #pragma unroll
            for (int j = 0; j < 8; ++j) {
                int d = vc * 8 + j;
                unsigned w = (unsigned)va[j] | ((unsigned)vb[j] << 16);
                int blk = ((vkp >> 3) + (d >> 3)) & 7;
                *(unsigned*)&Vt_s[d][blk * 8 + (vkp & 7)] = w;
            }
        }
        __syncthreads();                          // Vt(i+1) ready; K loads drained
    }

    // ---- 4-way merge (par x h2) per sub, one round ----
    const int b_ = bh >> 4, head = bh & 15;
    if (wid >= 2) {
        float* dstp = carve + (size_t)(wid - 2) * 2176 + lane * 34;
        dstp[0] = m; dstp[1] = l;
        #pragma unroll
        for (int db = 0; db < 2; ++db)
            #pragma unroll
            for (int k = 0; k < 16; ++k) dstp[2 + db * 16 + k] = po[db][k];
    }
    __syncthreads();
    if (wid < 2) {
        const float* p0 = carve + (size_t)(wid + 0) * 2176 + lane * 34;
        const float* p1 = carve + (size_t)(wid + 2) * 2176 + lane * 34;
        const float* p2 = carve + (size_t)(wid + 4) * 2176 + lane * 34;
        float m0 = p0[0], l0 = p0[1], m1 = p1[0], l1 = p1[1], m2 = p2[0], l2 = p2[1];
        float mf = fmaxf(fmaxf(m, m0), fmaxf(m1, m2));
        float c  = __expf(m - mf), c0 = __expf(m0 - mf);
        float c1 = __expf(m1 - mf), c2 = __expf(m2 - mf);
        float lf = l * c + l0 * c0 + l1 * c1 + l2 * c2;
        float inv = 1.0f / lf;
        const int qg2 = qt * 64 + wid * 32 + l31;
        ushort_t* orow = AO + ((size_t)(b_ * Tn + qg2)) * Dn + head * HDn;
        #pragma unroll
        for (int db = 0; db < 2; ++db) {
            #pragma unroll
            for (int rq = 0; rq < 4; ++rq) {
                u16x4 o4;
                #pragma unroll
                for (int rr = 0; rr < 4; ++rr) {
                    int k = rq * 4 + rr;
                    float v = (po[db][k] * c + p0[2 + db * 16 + k] * c0 +
                               p1[2 + db * 16 + k] * c1 + p2[2 + db * 16 + k] * c2) * inv;
                    o4[rr] = f2b(v);
                }
                *(u16x4*)&orow[db * 32 + 8 * rq + 4 * h] = o4;
            }
        }
    }
}

// ---------------------------------------------------------------------------
extern "C" void kernel_launch(void* const* d_in, const int* in_sizes, int n_in,
                              void* d_out, int out_size, void* d_ws, size_t ws_size,
                              hipStream_t stream)
{
    const float* x     = (const float*)d_in[0];
    const float* Wqkv  = (const float*)d_in[1];
    const float* Wproj = (const float*)d_in[2];
    float* out = (float*)d_out;

    ushort_t* ws = (ushort_t*)d_ws;
    ushort_t* xb     = ws;
    ushort_t* Wqkvt  = xb     + 4194304;
    ushort_t* Wprojt = Wqkvt  + 3145728;
    ushort_t* Qb     = Wprojt + 1048576;
    ushort_t* Kb     = Qb     + 4194304;
    ushort_t* Vb     = Kb     + 4194304;
    ushort_t* AOb    = Vb     + 4194304;

    cvt_bf16_kernel<<<524288 / 256, 256, 0, stream>>>(x, xb);
    transpose_kernel<<<dim3(3072 / 32, 32), 256, 0, stream>>>(Wqkv, Wqkvt, 3072);
    transpose_kernel<<<dim3(1024 / 32, 32), 256, 0, stream>>>(Wproj, Wprojt, 1024);

    // QKV projection with fused RoPE
    gemm_kernel<0><<<dim3(3072 / 128, 4096 / 128), 256, 0, stream>>>(
        xb, Wqkvt, Qb, Kb, Vb, nullptr, 3072);

    // flash attention: one q-tile per block, big-first dispatch, bh-major
    attn_kernel<<<dim3(Bn * Hn, 32), 512, 0, stream>>>(Qb, Kb, Vb, AOb);

    gemm_kernel<1><<<dim3(1024 / 128, 4096 / 128), 256, 0, stream>>>(
        AOb, Wprojt, nullptr, nullptr, nullptr, out, 1024);
}

// Round 10
// 117.282 us; speedup vs baseline: 2.1371x; 1.0995x over previous
//
#include <hip/hip_runtime.h>
#include <hip/hip_bf16.h>
#include <math.h>

// Problem constants
#define Bn  2
#define Tn  2048
#define Dn  1024
#define Hn  16
#define HDn 64
// M = B*T = 4096

typedef __attribute__((ext_vector_type(8))) short short8;
typedef __attribute__((ext_vector_type(8))) unsigned short u16x8;
typedef __attribute__((ext_vector_type(4))) unsigned short u16x4;
typedef __attribute__((ext_vector_type(4))) float f32x4;
typedef __attribute__((ext_vector_type(16))) float f32x16;
typedef unsigned short ushort_t;

#define MFMA16(a, b, c) __builtin_amdgcn_mfma_f32_16x16x32_bf16((a), (b), (c), 0, 0, 0)
#define MFMA32(a, b, c) __builtin_amdgcn_mfma_f32_32x32x16_bf16((a), (b), (c), 0, 0, 0)

__device__ __forceinline__ unsigned short f2b(float f) {
    union { float f; unsigned u; } v; v.f = f;
    unsigned r = (v.u + 0x7FFFu + ((v.u >> 16) & 1u)) >> 16;   // RNE
    return (unsigned short)r;
}
__device__ __forceinline__ float b2f(unsigned short h) {
    union { unsigned u; float f; } v; v.u = ((unsigned)h) << 16;
    return v.f;
}
__device__ __forceinline__ void gload_lds16(const void* g, void* l) {
    __builtin_amdgcn_global_load_lds(
        (const __attribute__((address_space(1))) void*)g,
        (__attribute__((address_space(3))) void*)l, 16, 0, 0);
}
__device__ __forceinline__ unsigned cvt_pk(float lo, float hi) {
    unsigned r;
    asm("v_cvt_pk_bf16_f32 %0, %1, %2" : "=v"(r) : "v"(lo), "v"(hi));
    return r;
}
// permlane32_swap with DISTINCT SSA values only (b==a would coalesce registers)
__device__ __forceinline__ void plswap(unsigned &a, unsigned &b) {
    asm volatile("v_permlane32_swap_b32 %0, %1" : "+v"(a), "+v"(b));
}
__device__ __forceinline__ float xhalf_max(float v) {
    return fmaxf(v, __shfl_xor(v, 32));
}
__device__ __forceinline__ float xhalf_add(float v) {
    return v + __shfl_xor(v, 32);
}

// ---------------------------------------------------------------------------
// x (f32) -> bf16, vectorized
// ---------------------------------------------------------------------------
__global__ __launch_bounds__(256) void cvt_bf16_kernel(
    const float* __restrict__ in, ushort_t* __restrict__ out)
{
    int i = blockIdx.x * 256 + threadIdx.x;
    const float4* p = (const float4*)in;
    float4 a = p[i * 2], b = p[i * 2 + 1];
    u16x8 o;
    o[0] = f2b(a.x); o[1] = f2b(a.y); o[2] = f2b(a.z); o[3] = f2b(a.w);
    o[4] = f2b(b.x); o[5] = f2b(b.y); o[6] = f2b(b.z); o[7] = f2b(b.w);
    *(u16x8*)&out[i * 8] = o;
}

// ---------------------------------------------------------------------------
// W (1024 x N, f32) -> Wt (N x 1024, bf16). 32x32 tiles, 256 threads.
// ---------------------------------------------------------------------------
__global__ __launch_bounds__(256) void transpose_kernel(
    const float* __restrict__ W, ushort_t* __restrict__ Wt, int N)
{
    __shared__ float tile[32][33];
    const int n0 = blockIdx.x * 32, k0 = blockIdx.y * 32;
    const int tx = threadIdx.x & 31, ty = threadIdx.x >> 5;
    #pragma unroll
    for (int i = 0; i < 4; ++i)
        tile[ty + i * 8][tx] = W[(size_t)(k0 + ty + i * 8) * N + n0 + tx];
    __syncthreads();
    #pragma unroll
    for (int i = 0; i < 4; ++i)
        Wt[(size_t)(n0 + ty + i * 8) * 1024 + k0 + tx] = f2b(tile[tx][ty + i * 8]);
}

// ---------------------------------------------------------------------------
// bf16 MFMA GEMM, m97 tile + T3 minimum-2-phase prefetch:
//   prologue STAGE(buf0); barrier;
//   loop { STAGE(buf^1, t+1); ds_read+MFMA on buf; barrier (vmcnt drain); }
// One barrier per K-step; staging latency hides under MFMA phase.
// 2-D XCD chunking (each XCD: (gridDim.y/4) x (nbx/2) region).
// EPI==0: QKV scatter with fused RoPE. EPI==1: f32 C store.
// ---------------------------------------------------------------------------
template <int EPI>
__global__ __launch_bounds__(256) void gemm_kernel(
    const ushort_t* __restrict__ A, const ushort_t* __restrict__ Bt,
    ushort_t* __restrict__ Qo, ushort_t* __restrict__ Ko, ushort_t* __restrict__ Vo,
    float* __restrict__ C, int Ncols)
{
    __shared__ __align__(16) ushort_t As[2][128 * 32];
    __shared__ __align__(16) ushort_t Bs[2][128 * 32];
    const int tid  = threadIdx.x;
    const int lane = tid & 63, wid = tid >> 6;
    const int l15 = lane & 15, lh = lane >> 4;
    const int wr = wid >> 1, wc = wid & 1;

    // 2-D XCD chunk mapping (XCD = linear block id % 8)
    const int nbx = gridDim.x;
    const int bid = blockIdx.y * nbx + blockIdx.x;
    const int xcd = bid & 7, r = bid >> 3;
    const int xm = xcd >> 1, xn = xcd & 1;       // 4 x 2 XCD regions
    const int bmc = gridDim.y >> 2;
    const int bnc = nbx >> 1;
    const int rm = r % bmc, rn = r / bmc;        // bm fast -> B panel reused
    const int bm = (xm * bmc + rm) * 128;
    const int bn = (xn * bnc + rn) * 128;

    f32x4 acc[4][4];
    #pragma unroll
    for (int i = 0; i < 4; ++i)
        #pragma unroll
        for (int j = 0; j < 4; ++j) acc[i][j] = (f32x4){0.f, 0.f, 0.f, 0.f};

    const ushort_t* Ag = A  + (size_t)bm * 1024;
    const ushort_t* Bg = Bt + (size_t)bn * 1024;

    // stage K-tile k0 into buffer `buf`
    auto STAGE = [&](int k0, int buf) {
        #pragma unroll
        for (int i = 0; i < 2; ++i) {
            int idx = i * 256 + tid;              // 0..511
            int row = idx >> 2, kc = idx & 3;
            int src_k = k0 + ((kc ^ (row & 3)) * 8);
            gload_lds16(Ag + (size_t)row * 1024 + src_k, &As[buf][idx * 8]);
            gload_lds16(Bg + (size_t)row * 1024 + src_k, &Bs[buf][idx * 8]);
        }
    };

    STAGE(0, 0);
    __syncthreads();                              // drains prologue loads

    for (int t = 0; t < 32; ++t) {
        const int cur = t & 1;
        if (t + 1 < 32) STAGE((t + 1) * 32, cur ^ 1);   // prefetch next tile

        short8 a[4], b[4];
        #pragma unroll
        for (int mi = 0; mi < 4; ++mi) {
            int ra = wr * 64 + mi * 16 + l15;
            a[mi] = *(const short8*)&As[cur][ra * 32 + ((lh ^ (ra & 3)) * 8)];
        }
        #pragma unroll
        for (int nj = 0; nj < 4; ++nj) {
            int rb = wc * 64 + nj * 16 + l15;
            b[nj] = *(const short8*)&Bs[cur][rb * 32 + ((lh ^ (rb & 3)) * 8)];
        }
        __builtin_amdgcn_s_setprio(1);
        #pragma unroll
        for (int mi = 0; mi < 4; ++mi)
            #pragma unroll
            for (int nj = 0; nj < 4; ++nj)
                acc[mi][nj] = MFMA16(a[mi], b[nj], acc[mi][nj]);
        __builtin_amdgcn_s_setprio(0);

        __syncthreads();   // vmcnt(0)+lgkmcnt(0) drain: prefetch landed, buf free
    }

    if (EPI == 0) {
        const int n0 = bn + wc * 64;          // head-aligned 64-col block
        const int i3 = n0 >> 10;              // 0=q, 1=k, 2=v
        const int hh = (n0 >> 6) & 15;
        if (i3 == 2) {
            #pragma unroll
            for (int mi = 0; mi < 4; ++mi)
                #pragma unroll
                for (int r2 = 0; r2 < 4; ++r2) {
                    int m = bm + wr * 64 + mi * 16 + lh * 4 + r2;
                    int b_ = m >> 11, t = m & 2047;
                    size_t ob = ((size_t)((b_ * Hn + hh) * Tn) + t) * HDn;
                    #pragma unroll
                    for (int nj = 0; nj < 4; ++nj)
                        Vo[ob + nj * 16 + l15] = f2b(acc[mi][nj][r2]);
                }
        } else {
            ushort_t* dst = i3 ? Ko : Qo;
            const float sc = i3 ? 1.0f : 0.125f;       // fold 1/sqrt(HD) into q
            const float inv0 = __powf(10000.0f, -(float)l15 * (1.0f / 32.0f));
            const float inv1 = __powf(10000.0f, -(float)(16 + l15) * (1.0f / 32.0f));
            #pragma unroll
            for (int mi = 0; mi < 4; ++mi)
                #pragma unroll
                for (int r2 = 0; r2 < 4; ++r2) {
                    int m = bm + wr * 64 + mi * 16 + lh * 4 + r2;
                    int b_ = m >> 11, t = m & 2047;
                    size_t ob = ((size_t)((b_ * Hn + hh) * Tn) + t) * HDn;
                    float tf = (float)t;
                    #pragma unroll
                    for (int nj = 0; nj < 2; ++nj) {
                        float fr = tf * (nj ? inv1 : inv0);
                        float cc, ss;
                        __sincosf(fr, &ss, &cc);
                        float v0 = acc[mi][nj][r2], v1 = acc[mi][nj + 2][r2];
                        int j = nj * 16 + l15;
                        dst[ob + j]      = f2b((v0 * cc - v1 * ss) * sc);
                        dst[ob + j + 32] = f2b((v1 * cc + v0 * ss) * sc);
                    }
                }
        }
    } else {
        #pragma unroll
        for (int mi = 0; mi < 4; ++mi)
            #pragma unroll
            for (int nj = 0; nj < 4; ++nj)
                #pragma unroll
                for (int r2 = 0; r2 < 4; ++r2) {
                    int m = bm + wr * 64 + mi * 16 + lh * 4 + r2;
                    int n = bn + wc * 64 + nj * 16 + l15;
                    C[(size_t)m * 1024 + n] = acc[mi][nj][r2];
                }
    }
}

// ---------------------------------------------------------------------------
// Flash attention v5.1 (unchanged from R9): one q-tile per block, parity-
// split KV, single state, single-buffered Vt, dbuf K. LDS 52KB -> 3 blk/CU.
// Grid (32 bh fast, 32 slot), qt = 31 - slot (LPT), XCD = bh%8.
// ---------------------------------------------------------------------------
#define ATTN_STEP(PO, MM, LL)                                                   \
  do {                                                                          \
    f32x16 st;                                                                  \
    _Pragma("unroll") for (int k = 0; k < 16; ++k) st[k] = 0.f;                 \
    __builtin_amdgcn_s_setprio(1);                                              \
    {                                                                           \
      const int keyr = h2 * 32 + l31;                                          \
      const ushort_t* kbase = &Ks_c[cur * 4096 + keyr * 64];                    \
      _Pragma("unroll") for (int dk = 0; dk < 4; ++dk) {                        \
        short8 kf = *(const short8*)(kbase + (((dk * 2 + h) ^ (l31 & 7)) * 8)); \
        st = MFMA32(kf, qf[dk], st);                                            \
      }                                                                         \
    }                                                                           \
    __builtin_amdgcn_s_setprio(0);                                              \
    if (kt == qt) {                                                             \
      const int qloc = sub * 32 + l31;                                          \
      _Pragma("unroll") for (int r = 0; r < 16; ++r) {                          \
        int keyloc = h2 * 32 + (r & 3) + 8 * (r >> 2) + 4 * h;                  \
        if (keyloc > qloc) st[r] = -1e30f;                                      \
      }                                                                         \
    }                                                                           \
    float t8[8];                                                                \
    _Pragma("unroll") for (int k = 0; k < 8; ++k) t8[k] = fmaxf(st[k], st[k + 8]); \
    _Pragma("unroll") for (int stp = 4; stp >= 1; stp >>= 1)                    \
      _Pragma("unroll") for (int k = 0; k < stp; ++k) t8[k] = fmaxf(t8[k], t8[k + stp]); \
    float mt = xhalf_max(t8[0]);                                                \
    float mnew = fmaxf(MM, mt);                                                 \
    float cr = __expf(MM - mnew);                                               \
    MM = mnew;                                                                  \
    _Pragma("unroll") for (int k = 0; k < 16; ++k) st[k] = __expf(st[k] - mnew); \
    _Pragma("unroll") for (int k = 0; k < 8; ++k) t8[k] = st[k] + st[k + 8];    \
    _Pragma("unroll") for (int stp = 4; stp >= 1; stp >>= 1)                    \
      _Pragma("unroll") for (int k = 0; k < stp; ++k) t8[k] += t8[k + stp];     \
    float ls = xhalf_add(t8[0]);                                                \
    LL = LL * cr + ls;                                                          \
    _Pragma("unroll") for (int db = 0; db < 2; ++db)                            \
      _Pragma("unroll") for (int k = 0; k < 16; ++k) PO[db][k] *= cr;           \
    {                                                                           \
      unsigned w0 = cvt_pk(st[0], st[1]);   unsigned w1 = cvt_pk(st[2], st[3]); \
      unsigned w2 = cvt_pk(st[4], st[5]);   unsigned w3 = cvt_pk(st[6], st[7]); \
      unsigned w4 = cvt_pk(st[8], st[9]);   unsigned w5 = cvt_pk(st[10], st[11]); \
      unsigned w6 = cvt_pk(st[12], st[13]); unsigned w7 = cvt_pk(st[14], st[15]); \
      plswap(w0, w2); plswap(w1, w3); plswap(w4, w6); plswap(w5, w7);           \
      union { unsigned u[4]; short8 s8; } f0, f1;                               \
      f0.u[0] = w0; f0.u[1] = w1; f0.u[2] = w2; f0.u[3] = w3;                   \
      f1.u[0] = w4; f1.u[1] = w5; f1.u[2] = w6; f1.u[3] = w7;                   \
      __builtin_amdgcn_s_setprio(1);                                            \
      _Pragma("unroll") for (int db = 0; db < 2; ++db) {                        \
        const int d = db * 32 + l31;                                            \
        const int ck0 = 4 * h2 + h;                                             \
        short8 vf0 = *(const short8*)&Vt_c[d][((ck0 + (d >> 3)) & 7) * 8];      \
        PO[db] = MFMA32(vf0, f0.s8, PO[db]);                                    \
        const int ck1 = 4 * h2 + 2 + h;                                         \
        short8 vf1 = *(const short8*)&Vt_c[d][((ck1 + (d >> 3)) & 7) * 8];      \
        PO[db] = MFMA32(vf1, f1.s8, PO[db]);                                    \
      }                                                                         \
      __builtin_amdgcn_s_setprio(0);                                            \
    }                                                                           \
  } while (0)

__global__ __launch_bounds__(512, 4) void attn_kernel(
    const ushort_t* __restrict__ Q, const ushort_t* __restrict__ K,
    const ushort_t* __restrict__ V, ushort_t* __restrict__ AO)
{
    __shared__ __align__(16) char smem[52224];
    ushort_t* KsE = (ushort_t*)smem;                          // [2][4096]
    ushort_t (*VtE)[72] = (ushort_t(*)[72])(smem + 16384);    // [64][72]
    ushort_t* KsO = (ushort_t*)(smem + 25600);
    ushort_t (*VtO)[72] = (ushort_t(*)[72])(smem + 41984);
    float* carve = (float*)smem;

    const int tid = threadIdx.x;
    const int lane = tid & 63, wid = tid >> 6;
    const int l31 = lane & 31, h = lane >> 5;
    const int bh = blockIdx.x;                // XCD = bh%8 (bh fast)
    const int qt = 31 - blockIdx.y;           // big blocks first (LPT backfill)
    const int sub = wid & 1, h2 = (wid >> 1) & 1, par = wid >> 2;
    const size_t base = (size_t)bh * (Tn * HDn);
    const int nIter = (qt >> 1) + 1;

    const int s = tid >> 8;
    const int ltid = tid & 255;
    ushort_t* Ks_s = s ? KsO : KsE;
    ushort_t (*Vt_s)[72] = s ? VtO : VtE;
    ushort_t* Ks_c = par ? KsO : KsE;
    ushort_t (*Vt_c)[72] = par ? VtO : VtE;
    const int vkp = (ltid >> 3) * 2, vc = ltid & 7;

    short8 qf[4];
    {
        const ushort_t* qp = Q + base + (size_t)(qt * 64 + sub * 32 + l31) * 64 + h * 8;
        #pragma unroll
        for (int dk = 0; dk < 4; ++dk) qf[dk] = *(const short8*)(qp + dk * 16);
    }

    f32x16 po[2];
    #pragma unroll
    for (int db = 0; db < 2; ++db)
        #pragma unroll
        for (int k = 0; k < 16; ++k) po[db][k] = 0.f;
    float m = -INFINITY, l = 0.f;

    u16x8 va, vb;
    {
        const ushort_t* ks = K + base + (size_t)s * 4096;
        #pragma unroll
        for (int i = 0; i < 2; ++i) {
            int idx = i * 256 + ltid, key = idx >> 3, c = idx & 7;
            gload_lds16(ks + key * 64 + ((c ^ (key & 7)) * 8), &Ks_s[idx * 8]);
        }
        const ushort_t* v0 = V + base + (size_t)s * 4096 + (size_t)vkp * 64 + vc * 8;
        va = *(const u16x8*)v0;
        vb = *(const u16x8*)(v0 + 64);
        #pragma unroll
        for (int j = 0; j < 8; ++j) {
            int d = vc * 8 + j;
            unsigned w = (unsigned)va[j] | ((unsigned)vb[j] << 16);
            int blk = ((vkp >> 3) + (d >> 3)) & 7;
            *(unsigned*)&Vt_s[d][blk * 8 + (vkp & 7)] = w;
        }
    }
    __syncthreads();

    for (int i = 0; i < nIter; ++i) {
        const int cur = i & 1;
        const int ktn = 2 * (i + 1) + s;
        const bool doPf = (ktn <= qt);
        if (doPf) {
            const ushort_t* ks = K + base + (size_t)ktn * 4096;
            #pragma unroll
            for (int ii = 0; ii < 2; ++ii) {
                int idx = ii * 256 + ltid, key = idx >> 3, c = idx & 7;
                gload_lds16(ks + key * 64 + ((c ^ (key & 7)) * 8),
                            &Ks_s[(cur ^ 1) * 4096 + idx * 8]);
            }
            const ushort_t* v0 = V + base + (size_t)ktn * 4096 + (size_t)vkp * 64 + vc * 8;
            va = *(const u16x8*)v0;
            vb = *(const u16x8*)(v0 + 64);
        }

        const int kt = 2 * i + par;
        if (kt <= qt && !(kt == qt && h2 > sub)) {
            ATTN_STEP(po, m, l);
        }

        __syncthreads();                          // all waves done reading Vt
        if (doPf) {
            #pragma unroll
            for (int j = 0; j < 8; ++j) {
                int d = vc * 8 + j;
                unsigned w = (unsigned)va[j] | ((unsigned)vb[j] << 16);
                int blk = ((vkp >> 3) + (d >> 3)) & 7;
                *(unsigned*)&Vt_s[d][blk * 8 + (vkp & 7)] = w;
            }
        }
        __syncthreads();                          // Vt(i+1) ready; K loads drained
    }

    // ---- 4-way merge (par x h2) per sub, one round ----
    const int b_ = bh >> 4, head = bh & 15;
    if (wid >= 2) {
        float* dstp = carve + (size_t)(wid - 2) * 2176 + lane * 34;
        dstp[0] = m; dstp[1] = l;
        #pragma unroll
        for (int db = 0; db < 2; ++db)
            #pragma unroll
            for (int k = 0; k < 16; ++k) dstp[2 + db * 16 + k] = po[db][k];
    }
    __syncthreads();
    if (wid < 2) {
        const float* p0 = carve + (size_t)(wid + 0) * 2176 + lane * 34;
        const float* p1 = carve + (size_t)(wid + 2) * 2176 + lane * 34;
        const float* p2 = carve + (size_t)(wid + 4) * 2176 + lane * 34;
        float m0 = p0[0], l0 = p0[1], m1 = p1[0], l1 = p1[1], m2 = p2[0], l2 = p2[1];
        float mf = fmaxf(fmaxf(m, m0), fmaxf(m1, m2));
        float c  = __expf(m - mf), c0 = __expf(m0 - mf);
        float c1 = __expf(m1 - mf), c2 = __expf(m2 - mf);
        float lf = l * c + l0 * c0 + l1 * c1 + l2 * c2;
        float inv = 1.0f / lf;
        const int qg2 = qt * 64 + wid * 32 + l31;
        ushort_t* orow = AO + ((size_t)(b_ * Tn + qg2)) * Dn + head * HDn;
        #pragma unroll
        for (int db = 0; db < 2; ++db) {
            #pragma unroll
            for (int rq = 0; rq < 4; ++rq) {
                u16x4 o4;
                #pragma unroll
                for (int rr = 0; rr < 4; ++rr) {
                    int k = rq * 4 + rr;
                    float v = (po[db][k] * c + p0[2 + db * 16 + k] * c0 +
                               p1[2 + db * 16 + k] * c1 + p2[2 + db * 16 + k] * c2) * inv;
                    o4[rr] = f2b(v);
                }
                *(u16x4*)&orow[db * 32 + 8 * rq + 4 * h] = o4;
            }
        }
    }
}

// ---------------------------------------------------------------------------
extern "C" void kernel_launch(void* const* d_in, const int* in_sizes, int n_in,
                              void* d_out, int out_size, void* d_ws, size_t ws_size,
                              hipStream_t stream)
{
    const float* x     = (const float*)d_in[0];
    const float* Wqkv  = (const float*)d_in[1];
    const float* Wproj = (const float*)d_in[2];
    float* out = (float*)d_out;

    ushort_t* ws = (ushort_t*)d_ws;
    ushort_t* xb     = ws;
    ushort_t* Wqkvt  = xb     + 4194304;
    ushort_t* Wprojt = Wqkvt  + 3145728;
    ushort_t* Qb     = Wprojt + 1048576;
    ushort_t* Kb     = Qb     + 4194304;
    ushort_t* Vb     = Kb     + 4194304;
    ushort_t* AOb    = Vb     + 4194304;

    cvt_bf16_kernel<<<524288 / 256, 256, 0, stream>>>(x, xb);
    transpose_kernel<<<dim3(3072 / 32, 32), 256, 0, stream>>>(Wqkv, Wqkvt, 3072);
    transpose_kernel<<<dim3(1024 / 32, 32), 256, 0, stream>>>(Wproj, Wprojt, 1024);

    // QKV projection with fused RoPE
    gemm_kernel<0><<<dim3(3072 / 128, 4096 / 128), 256, 0, stream>>>(
        xb, Wqkvt, Qb, Kb, Vb, nullptr, 3072);

    // flash attention: one q-tile per block, big-first dispatch, bh-major
    attn_kernel<<<dim3(Bn * Hn, 32), 512, 0, stream>>>(Qb, Kb, Vb, AOb);

    gemm_kernel<1><<<dim3(1024 / 128, 4096 / 128), 256, 0, stream>>>(
        AOb, Wprojt, nullptr, nullptr, nullptr, out, 1024);
}

// Round 11
// 114.238 us; speedup vs baseline: 2.1940x; 1.0266x over previous
//
#include <hip/hip_runtime.h>
#include <hip/hip_bf16.h>
#include <math.h>

// Problem constants
#define Bn  2
#define Tn  2048
#define Dn  1024
#define Hn  16
#define HDn 64
// M = B*T = 4096

typedef __attribute__((ext_vector_type(8))) short short8;
typedef __attribute__((ext_vector_type(8))) unsigned short u16x8;
typedef __attribute__((ext_vector_type(4))) unsigned short u16x4;
typedef __attribute__((ext_vector_type(4))) float f32x4;
typedef __attribute__((ext_vector_type(16))) float f32x16;
typedef unsigned short ushort_t;

#define MFMA16(a, b, c) __builtin_amdgcn_mfma_f32_16x16x32_bf16((a), (b), (c), 0, 0, 0)
#define MFMA32(a, b, c) __builtin_amdgcn_mfma_f32_32x32x16_bf16((a), (b), (c), 0, 0, 0)

__device__ __forceinline__ unsigned short f2b(float f) {
    union { float f; unsigned u; } v; v.f = f;
    unsigned r = (v.u + 0x7FFFu + ((v.u >> 16) & 1u)) >> 16;   // RNE
    return (unsigned short)r;
}
__device__ __forceinline__ float b2f(unsigned short h) {
    union { unsigned u; float f; } v; v.u = ((unsigned)h) << 16;
    return v.f;
}
__device__ __forceinline__ void gload_lds16(const void* g, void* l) {
    __builtin_amdgcn_global_load_lds(
        (const __attribute__((address_space(1))) void*)g,
        (__attribute__((address_space(3))) void*)l, 16, 0, 0);
}
__device__ __forceinline__ unsigned cvt_pk(float lo, float hi) {
    unsigned r;
    asm("v_cvt_pk_bf16_f32 %0, %1, %2" : "=v"(r) : "v"(lo), "v"(hi));
    return r;
}
// permlane32_swap with DISTINCT SSA values only (b==a would coalesce registers)
__device__ __forceinline__ void plswap(unsigned &a, unsigned &b) {
    asm volatile("v_permlane32_swap_b32 %0, %1" : "+v"(a), "+v"(b));
}
__device__ __forceinline__ float xhalf_max(float v) {
    return fmaxf(v, __shfl_xor(v, 32));
}
__device__ __forceinline__ float xhalf_add(float v) {
    return v + __shfl_xor(v, 32);
}
// bare 2^x (scores are kept in log2 domain; log2e folded into Q scale)
__device__ __forceinline__ float fexp2(float x) {
    float r;
    asm("v_exp_f32 %0, %1" : "=v"(r) : "v"(x));
    return r;
}

// ---------------------------------------------------------------------------
// x (f32) -> bf16, vectorized
// ---------------------------------------------------------------------------
__global__ __launch_bounds__(256) void cvt_bf16_kernel(
    const float* __restrict__ in, ushort_t* __restrict__ out)
{
    int i = blockIdx.x * 256 + threadIdx.x;
    const float4* p = (const float4*)in;
    float4 a = p[i * 2], b = p[i * 2 + 1];
    u16x8 o;
    o[0] = f2b(a.x); o[1] = f2b(a.y); o[2] = f2b(a.z); o[3] = f2b(a.w);
    o[4] = f2b(b.x); o[5] = f2b(b.y); o[6] = f2b(b.z); o[7] = f2b(b.w);
    *(u16x8*)&out[i * 8] = o;
}

// ---------------------------------------------------------------------------
// W (1024 x N, f32) -> Wt (N x 1024, bf16). 32x32 tiles, 256 threads.
// ---------------------------------------------------------------------------
__global__ __launch_bounds__(256) void transpose_kernel(
    const float* __restrict__ W, ushort_t* __restrict__ Wt, int N)
{
    __shared__ float tile[32][33];
    const int n0 = blockIdx.x * 32, k0 = blockIdx.y * 32;
    const int tx = threadIdx.x & 31, ty = threadIdx.x >> 5;
    #pragma unroll
    for (int i = 0; i < 4; ++i)
        tile[ty + i * 8][tx] = W[(size_t)(k0 + ty + i * 8) * N + n0 + tx];
    __syncthreads();
    #pragma unroll
    for (int i = 0; i < 4; ++i)
        Wt[(size_t)(n0 + ty + i * 8) * 1024 + k0 + tx] = f2b(tile[tx][ty + i * 8]);
}

// ---------------------------------------------------------------------------
// bf16 MFMA GEMM, m97 tile + T3 minimum-2-phase prefetch.
// 2-D XCD chunking. EPI==0: QKV scatter with fused RoPE; Q is scaled by
// 0.125 * log2(e) so attention scores land in log2 domain.
// ---------------------------------------------------------------------------
template <int EPI>
__global__ __launch_bounds__(256) void gemm_kernel(
    const ushort_t* __restrict__ A, const ushort_t* __restrict__ Bt,
    ushort_t* __restrict__ Qo, ushort_t* __restrict__ Ko, ushort_t* __restrict__ Vo,
    float* __restrict__ C, int Ncols)
{
    __shared__ __align__(16) ushort_t As[2][128 * 32];
    __shared__ __align__(16) ushort_t Bs[2][128 * 32];
    const int tid  = threadIdx.x;
    const int lane = tid & 63, wid = tid >> 6;
    const int l15 = lane & 15, lh = lane >> 4;
    const int wr = wid >> 1, wc = wid & 1;

    // 2-D XCD chunk mapping (XCD = linear block id % 8)
    const int nbx = gridDim.x;
    const int bid = blockIdx.y * nbx + blockIdx.x;
    const int xcd = bid & 7, r = bid >> 3;
    const int xm = xcd >> 1, xn = xcd & 1;       // 4 x 2 XCD regions
    const int bmc = gridDim.y >> 2;
    const int bnc = nbx >> 1;
    const int rm = r % bmc, rn = r / bmc;        // bm fast -> B panel reused
    const int bm = (xm * bmc + rm) * 128;
    const int bn = (xn * bnc + rn) * 128;

    f32x4 acc[4][4];
    #pragma unroll
    for (int i = 0; i < 4; ++i)
        #pragma unroll
        for (int j = 0; j < 4; ++j) acc[i][j] = (f32x4){0.f, 0.f, 0.f, 0.f};

    const ushort_t* Ag = A  + (size_t)bm * 1024;
    const ushort_t* Bg = Bt + (size_t)bn * 1024;

    auto STAGE = [&](int k0, int buf) {
        #pragma unroll
        for (int i = 0; i < 2; ++i) {
            int idx = i * 256 + tid;
            int row = idx >> 2, kc = idx & 3;
            int src_k = k0 + ((kc ^ (row & 3)) * 8);
            gload_lds16(Ag + (size_t)row * 1024 + src_k, &As[buf][idx * 8]);
            gload_lds16(Bg + (size_t)row * 1024 + src_k, &Bs[buf][idx * 8]);
        }
    };

    STAGE(0, 0);
    __syncthreads();

    for (int t = 0; t < 32; ++t) {
        const int cur = t & 1;
        if (t + 1 < 32) STAGE((t + 1) * 32, cur ^ 1);

        short8 a[4], b[4];
        #pragma unroll
        for (int mi = 0; mi < 4; ++mi) {
            int ra = wr * 64 + mi * 16 + l15;
            a[mi] = *(const short8*)&As[cur][ra * 32 + ((lh ^ (ra & 3)) * 8)];
        }
        #pragma unroll
        for (int nj = 0; nj < 4; ++nj) {
            int rb = wc * 64 + nj * 16 + l15;
            b[nj] = *(const short8*)&Bs[cur][rb * 32 + ((lh ^ (rb & 3)) * 8)];
        }
        __builtin_amdgcn_s_setprio(1);
        #pragma unroll
        for (int mi = 0; mi < 4; ++mi)
            #pragma unroll
            for (int nj = 0; nj < 4; ++nj)
                acc[mi][nj] = MFMA16(a[mi], b[nj], acc[mi][nj]);
        __builtin_amdgcn_s_setprio(0);

        __syncthreads();
    }

    if (EPI == 0) {
        const int n0 = bn + wc * 64;
        const int i3 = n0 >> 10;              // 0=q, 1=k, 2=v
        const int hh = (n0 >> 6) & 15;
        if (i3 == 2) {
            #pragma unroll
            for (int mi = 0; mi < 4; ++mi)
                #pragma unroll
                for (int r2 = 0; r2 < 4; ++r2) {
                    int m = bm + wr * 64 + mi * 16 + lh * 4 + r2;
                    int b_ = m >> 11, t = m & 2047;
                    size_t ob = ((size_t)((b_ * Hn + hh) * Tn) + t) * HDn;
                    #pragma unroll
                    for (int nj = 0; nj < 4; ++nj)
                        Vo[ob + nj * 16 + l15] = f2b(acc[mi][nj][r2]);
                }
        } else {
            ushort_t* dst = i3 ? Ko : Qo;
            // q scale = 1/sqrt(HD) * log2(e)  -> scores in log2 domain
            const float sc = i3 ? 1.0f : 0.18033688f;
            const float inv0 = __powf(10000.0f, -(float)l15 * (1.0f / 32.0f));
            const float inv1 = __powf(10000.0f, -(float)(16 + l15) * (1.0f / 32.0f));
            #pragma unroll
            for (int mi = 0; mi < 4; ++mi)
                #pragma unroll
                for (int r2 = 0; r2 < 4; ++r2) {
                    int m = bm + wr * 64 + mi * 16 + lh * 4 + r2;
                    int b_ = m >> 11, t = m & 2047;
                    size_t ob = ((size_t)((b_ * Hn + hh) * Tn) + t) * HDn;
                    float tf = (float)t;
                    #pragma unroll
                    for (int nj = 0; nj < 2; ++nj) {
                        float fr = tf * (nj ? inv1 : inv0);
                        float cc, ss;
                        __sincosf(fr, &ss, &cc);
                        float v0 = acc[mi][nj][r2], v1 = acc[mi][nj + 2][r2];
                        int j = nj * 16 + l15;
                        dst[ob + j]      = f2b((v0 * cc - v1 * ss) * sc);
                        dst[ob + j + 32] = f2b((v1 * cc + v0 * ss) * sc);
                    }
                }
        }
    } else {
        #pragma unroll
        for (int mi = 0; mi < 4; ++mi)
            #pragma unroll
            for (int nj = 0; nj < 4; ++nj)
                #pragma unroll
                for (int r2 = 0; r2 < 4; ++r2) {
                    int m = bm + wr * 64 + mi * 16 + lh * 4 + r2;
                    int n = bn + wc * 64 + nj * 16 + l15;
                    C[(size_t)m * 1024 + n] = acc[mi][nj][r2];
                }
    }
}

// ---------------------------------------------------------------------------
// Flash attention v5.2: v5.1 structure + exp2-domain softmax + T13 defer-max.
// Scores arrive in log2 domain (log2e folded into Q). Rescale of O/l is
// SKIPPED whenever the tile max stays within 2^11 of the running max
// (wave-uniform branch); P is then bounded by 2048 (bf16/f32 headroom ok).
// ---------------------------------------------------------------------------
#define ATTN_STEP(PO, MM, LL)                                                   \
  do {                                                                          \
    f32x16 st;                                                                  \
    _Pragma("unroll") for (int k = 0; k < 16; ++k) st[k] = 0.f;                 \
    __builtin_amdgcn_s_setprio(1);                                              \
    {                                                                           \
      const int keyr = h2 * 32 + l31;                                          \
      const ushort_t* kbase = &Ks_c[cur * 4096 + keyr * 64];                    \
      _Pragma("unroll") for (int dk = 0; dk < 4; ++dk) {                        \
        short8 kf = *(const short8*)(kbase + (((dk * 2 + h) ^ (l31 & 7)) * 8)); \
        st = MFMA32(kf, qf[dk], st);                                            \
      }                                                                         \
    }                                                                           \
    __builtin_amdgcn_s_setprio(0);                                              \
    if (kt == qt) {                                                             \
      const int qloc = sub * 32 + l31;                                          \
      _Pragma("unroll") for (int r = 0; r < 16; ++r) {                          \
        int keyloc = h2 * 32 + (r & 3) + 8 * (r >> 2) + 4 * h;                  \
        if (keyloc > qloc) st[r] = -1e30f;                                      \
      }                                                                         \
    }                                                                           \
    float t8[8];                                                                \
    _Pragma("unroll") for (int k = 0; k < 8; ++k) t8[k] = fmaxf(st[k], st[k + 8]); \
    _Pragma("unroll") for (int stp = 4; stp >= 1; stp >>= 1)                    \
      _Pragma("unroll") for (int k = 0; k < stp; ++k) t8[k] = fmaxf(t8[k], t8[k + stp]); \
    float mt = xhalf_max(t8[0]);                                                \
    if (!__all(mt <= MM + 11.0f)) {    /* T13: rescale only on real growth */   \
      float mnew = fmaxf(MM, mt);                                               \
      float cr = fexp2(MM - mnew);                                              \
      MM = mnew;                                                                \
      LL *= cr;                                                                 \
      _Pragma("unroll") for (int db = 0; db < 2; ++db)                          \
        _Pragma("unroll") for (int k = 0; k < 16; ++k) PO[db][k] *= cr;         \
    }                                                                           \
    _Pragma("unroll") for (int k = 0; k < 16; ++k) st[k] = fexp2(st[k] - MM);   \
    _Pragma("unroll") for (int k = 0; k < 8; ++k) t8[k] = st[k] + st[k + 8];    \
    _Pragma("unroll") for (int stp = 4; stp >= 1; stp >>= 1)                    \
      _Pragma("unroll") for (int k = 0; k < stp; ++k) t8[k] += t8[k + stp];     \
    LL += xhalf_add(t8[0]);                                                     \
    {                                                                           \
      unsigned w0 = cvt_pk(st[0], st[1]);   unsigned w1 = cvt_pk(st[2], st[3]); \
      unsigned w2 = cvt_pk(st[4], st[5]);   unsigned w3 = cvt_pk(st[6], st[7]); \
      unsigned w4 = cvt_pk(st[8], st[9]);   unsigned w5 = cvt_pk(st[10], st[11]); \
      unsigned w6 = cvt_pk(st[12], st[13]); unsigned w7 = cvt_pk(st[14], st[15]); \
      plswap(w0, w2); plswap(w1, w3); plswap(w4, w6); plswap(w5, w7);           \
      union { unsigned u[4]; short8 s8; } f0, f1;                               \
      f0.u[0] = w0; f0.u[1] = w1; f0.u[2] = w2; f0.u[3] = w3;                   \
      f1.u[0] = w4; f1.u[1] = w5; f1.u[2] = w6; f1.u[3] = w7;                   \
      __builtin_amdgcn_s_setprio(1);                                            \
      _Pragma("unroll") for (int db = 0; db < 2; ++db) {                        \
        const int d = db * 32 + l31;                                            \
        const int ck0 = 4 * h2 + h;                                             \
        short8 vf0 = *(const short8*)&Vt_c[d][((ck0 + (d >> 3)) & 7) * 8];      \
        PO[db] = MFMA32(vf0, f0.s8, PO[db]);                                    \
        const int ck1 = 4 * h2 + 2 + h;                                         \
        short8 vf1 = *(const short8*)&Vt_c[d][((ck1 + (d >> 3)) & 7) * 8];      \
        PO[db] = MFMA32(vf1, f1.s8, PO[db]);                                    \
      }                                                                         \
      __builtin_amdgcn_s_setprio(0);                                            \
    }                                                                           \
  } while (0)

__global__ __launch_bounds__(512, 4) void attn_kernel(
    const ushort_t* __restrict__ Q, const ushort_t* __restrict__ K,
    const ushort_t* __restrict__ V, ushort_t* __restrict__ AO)
{
    __shared__ __align__(16) char smem[52224];
    ushort_t* KsE = (ushort_t*)smem;                          // [2][4096]
    ushort_t (*VtE)[72] = (ushort_t(*)[72])(smem + 16384);    // [64][72]
    ushort_t* KsO = (ushort_t*)(smem + 25600);
    ushort_t (*VtO)[72] = (ushort_t(*)[72])(smem + 41984);
    float* carve = (float*)smem;

    const int tid = threadIdx.x;
    const int lane = tid & 63, wid = tid >> 6;
    const int l31 = lane & 31, h = lane >> 5;
    const int bh = blockIdx.x;                // XCD = bh%8 (bh fast)
    const int qt = 31 - blockIdx.y;           // big blocks first (LPT backfill)
    const int sub = wid & 1, h2 = (wid >> 1) & 1, par = wid >> 2;
    const size_t base = (size_t)bh * (Tn * HDn);
    const int nIter = (qt >> 1) + 1;

    const int s = tid >> 8;
    const int ltid = tid & 255;
    ushort_t* Ks_s = s ? KsO : KsE;
    ushort_t (*Vt_s)[72] = s ? VtO : VtE;
    ushort_t* Ks_c = par ? KsO : KsE;
    ushort_t (*Vt_c)[72] = par ? VtO : VtE;
    const int vkp = (ltid >> 3) * 2, vc = ltid & 7;

    short8 qf[4];
    {
        const ushort_t* qp = Q + base + (size_t)(qt * 64 + sub * 32 + l31) * 64 + h * 8;
        #pragma unroll
        for (int dk = 0; dk < 4; ++dk) qf[dk] = *(const short8*)(qp + dk * 16);
    }

    f32x16 po[2];
    #pragma unroll
    for (int db = 0; db < 2; ++db)
        #pragma unroll
        for (int k = 0; k < 16; ++k) po[db][k] = 0.f;
    float m = -INFINITY, l = 0.f;

    u16x8 va, vb;
    {
        const ushort_t* ks = K + base + (size_t)s * 4096;
        #pragma unroll
        for (int i = 0; i < 2; ++i) {
            int idx = i * 256 + ltid, key = idx >> 3, c = idx & 7;
            gload_lds16(ks + key * 64 + ((c ^ (key & 7)) * 8), &Ks_s[idx * 8]);
        }
        const ushort_t* v0 = V + base + (size_t)s * 4096 + (size_t)vkp * 64 + vc * 8;
        va = *(const u16x8*)v0;
        vb = *(const u16x8*)(v0 + 64);
        #pragma unroll
        for (int j = 0; j < 8; ++j) {
            int d = vc * 8 + j;
            unsigned w = (unsigned)va[j] | ((unsigned)vb[j] << 16);
            int blk = ((vkp >> 3) + (d >> 3)) & 7;
            *(unsigned*)&Vt_s[d][blk * 8 + (vkp & 7)] = w;
        }
    }
    __syncthreads();

    for (int i = 0; i < nIter; ++i) {
        const int cur = i & 1;
        const int ktn = 2 * (i + 1) + s;
        const bool doPf = (ktn <= qt);
        if (doPf) {
            const ushort_t* ks = K + base + (size_t)ktn * 4096;
            #pragma unroll
            for (int ii = 0; ii < 2; ++ii) {
                int idx = ii * 256 + ltid, key = idx >> 3, c = idx & 7;
                gload_lds16(ks + key * 64 + ((c ^ (key & 7)) * 8),
                            &Ks_s[(cur ^ 1) * 4096 + idx * 8]);
            }
            const ushort_t* v0 = V + base + (size_t)ktn * 4096 + (size_t)vkp * 64 + vc * 8;
            va = *(const u16x8*)v0;
            vb = *(const u16x8*)(v0 + 64);
        }

        const int kt = 2 * i + par;
        if (kt <= qt && !(kt == qt && h2 > sub)) {
            ATTN_STEP(po, m, l);
        }

        __syncthreads();                          // all waves done reading Vt
        if (doPf) {
            #pragma unroll
            for (int j = 0; j < 8; ++j) {
                int d = vc * 8 + j;
                unsigned w = (unsigned)va[j] | ((unsigned)vb[j] << 16);
                int blk = ((vkp >> 3) + (d >> 3)) & 7;
                *(unsigned*)&Vt_s[d][blk * 8 + (vkp & 7)] = w;
            }
        }
        __syncthreads();                          // Vt(i+1) ready; K loads drained
    }

    // ---- 4-way merge (par x h2) per sub, one round (log2 domain) ----
    const int b_ = bh >> 4, head = bh & 15;
    if (wid >= 2) {
        float* dstp = carve + (size_t)(wid - 2) * 2176 + lane * 34;
        dstp[0] = m; dstp[1] = l;
        #pragma unroll
        for (int db = 0; db < 2; ++db)
            #pragma unroll
            for (int k = 0; k < 16; ++k) dstp[2 + db * 16 + k] = po[db][k];
    }
    __syncthreads();
    if (wid < 2) {
        const float* p0 = carve + (size_t)(wid + 0) * 2176 + lane * 34;
        const float* p1 = carve + (size_t)(wid + 2) * 2176 + lane * 34;
        const float* p2 = carve + (size_t)(wid + 4) * 2176 + lane * 34;
        float m0 = p0[0], l0 = p0[1], m1 = p1[0], l1 = p1[1], m2 = p2[0], l2 = p2[1];
        float mf = fmaxf(fmaxf(m, m0), fmaxf(m1, m2));
        float c  = fexp2(m - mf), c0 = fexp2(m0 - mf);
        float c1 = fexp2(m1 - mf), c2 = fexp2(m2 - mf);
        float lf = l * c + l0 * c0 + l1 * c1 + l2 * c2;
        float inv = 1.0f / lf;
        const int qg2 = qt * 64 + wid * 32 + l31;
        ushort_t* orow = AO + ((size_t)(b_ * Tn + qg2)) * Dn + head * HDn;
        #pragma unroll
        for (int db = 0; db < 2; ++db) {
            #pragma unroll
            for (int rq = 0; rq < 4; ++rq) {
                u16x4 o4;
                #pragma unroll
                for (int rr = 0; rr < 4; ++rr) {
                    int k = rq * 4 + rr;
                    float v = (po[db][k] * c + p0[2 + db * 16 + k] * c0 +
                               p1[2 + db * 16 + k] * c1 + p2[2 + db * 16 + k] * c2) * inv;
                    o4[rr] = f2b(v);
                }
                *(u16x4*)&orow[db * 32 + 8 * rq + 4 * h] = o4;
            }
        }
    }
}

// ---------------------------------------------------------------------------
extern "C" void kernel_launch(void* const* d_in, const int* in_sizes, int n_in,
                              void* d_out, int out_size, void* d_ws, size_t ws_size,
                              hipStream_t stream)
{
    const float* x     = (const float*)d_in[0];
    const float* Wqkv  = (const float*)d_in[1];
    const float* Wproj = (const float*)d_in[2];
    float* out = (float*)d_out;

    ushort_t* ws = (ushort_t*)d_ws;
    ushort_t* xb     = ws;
    ushort_t* Wqkvt  = xb     + 4194304;
    ushort_t* Wprojt = Wqkvt  + 3145728;
    ushort_t* Qb     = Wprojt + 1048576;
    ushort_t* Kb     = Qb     + 4194304;
    ushort_t* Vb     = Kb     + 4194304;
    ushort_t* AOb    = Vb     + 4194304;

    cvt_bf16_kernel<<<524288 / 256, 256, 0, stream>>>(x, xb);
    transpose_kernel<<<dim3(3072 / 32, 32), 256, 0, stream>>>(Wqkv, Wqkvt, 3072);
    transpose_kernel<<<dim3(1024 / 32, 32), 256, 0, stream>>>(Wproj, Wprojt, 1024);

    // QKV projection with fused RoPE (+ log2e folded into q scale)
    gemm_kernel<0><<<dim3(3072 / 128, 4096 / 128), 256, 0, stream>>>(
        xb, Wqkvt, Qb, Kb, Vb, nullptr, 3072);

    // flash attention: one q-tile per block, big-first dispatch, bh-major
    attn_kernel<<<dim3(Bn * Hn, 32), 512, 0, stream>>>(Qb, Kb, Vb, AOb);

    gemm_kernel<1><<<dim3(1024 / 128, 4096 / 128), 256, 0, stream>>>(
        AOb, Wprojt, nullptr, nullptr, nullptr, out, 1024);
}